// Round 8
// baseline (831.374 us; speedup 1.0000x reference)
//
#include <hip/hip_runtime.h>
#include <hip/hip_bf16.h>
#include <math.h>

typedef __hip_bfloat16 bf16;
typedef __attribute__((ext_vector_type(8))) short bf16x8;
typedef __attribute__((ext_vector_type(4))) float f32x4;

#define Bc   32
#define Hc   56
#define Wcc  56
#define Nc   3136
#define Cpc  32
#define Cac  96
#define EPSc 1e-5f
#define SCALEc 0.28867513459481287f   /* 1/sqrt(12) */

__device__ __forceinline__ float gelu_f(float x) {
    return 0.5f * x * (1.0f + erff(x * 0.7071067811865475f));
}

// raw v_exp_f32 (2^x). Fallback keeps correctness if builtin is absent.
__device__ __forceinline__ float fast_exp2(float x) {
#if defined(__has_builtin)
#if __has_builtin(__builtin_amdgcn_exp2f)
    return __builtin_amdgcn_exp2f(x);
#else
    return exp2f(x);
#endif
#else
    return exp2f(x);
#endif
}

// ---------------- LN1: (B,N,128) -> xa fp32 (B,N,96) + xab bf16 + xc_img (B,32,56,56) fp32
__global__ __launch_bounds__(256) void ln1_kernel(const float* __restrict__ x,
        const float* __restrict__ g, const float* __restrict__ be,
        float* __restrict__ xa, bf16* __restrict__ xab, float* __restrict__ xc_img)
{
    int wv = threadIdx.x >> 6, lane = threadIdx.x & 63;
    int row = blockIdx.x * 4 + wv;
    if (row >= Bc * Nc) return;
    const float* xr = x + (size_t)row * 128;
    float x0 = xr[lane];
    float x1 = xr[lane + 64];
    float s = x0 + x1, q = x0 * x0 + x1 * x1;
    for (int o = 32; o; o >>= 1) { s += __shfl_xor(s, o); q += __shfl_xor(q, o); }
    float mean = s * (1.f / 128.f);
    float inv = rsqrtf(q * (1.f / 128.f) - mean * mean + EPSc);
    int b = row / Nc, n = row % Nc;
    {
        int c = lane;
        float y = (x0 - mean) * inv * g[c] + be[c];
        if (c < Cpc) xc_img[(size_t)(b * Cpc + c) * Nc + n] = y;
        else { xa[(size_t)row * Cac + (c - Cpc)] = y;
               xab[(size_t)row * Cac + (c - Cpc)] = __float2bfloat16(y); }
    }
    {
        int c = lane + 64;
        float y = (x1 - mean) * inv * g[c] + be[c];
        xa[(size_t)row * Cac + (c - Cpc)] = y;
        xab[(size_t)row * Cac + (c - Cpc)] = __float2bfloat16(y);
    }
}

// ---------------- Haar DWT
__global__ void dwt_kernel(const float* __restrict__ src, int cs, int h, int w,
                           int h2, int w2, float* __restrict__ sub)
{
    int t = blockIdx.x * blockDim.x + threadIdx.x;
    int total = Bc * 32 * h2 * w2;
    if (t >= total) return;
    int xx = t % w2; int r = t / w2;
    int yy = r % h2; r /= h2;
    int c = r & 31; int b = r >> 5;
    const float* sp = src + (size_t)cs * (b * 32 + c) * h * w;
    int y0 = yy * 2, x0 = xx * 2;
    bool xe = (x0 + 1 < w), ye = (y0 + 1 < h);
    float a  = sp[y0 * w + x0];
    float bb = xe ? sp[y0 * w + x0 + 1] : 0.f;
    float cc = ye ? sp[(y0 + 1) * w + x0] : 0.f;
    float dd = (xe && ye) ? sp[(y0 + 1) * w + x0 + 1] : 0.f;
    size_t pl = (size_t)h2 * w2;
    size_t ob = (size_t)(b * 128 + c * 4) * pl + yy * w2 + xx;
    sub[ob]          = ( a + bb + cc + dd) * 0.5f;
    sub[ob + pl]     = (-a - bb + cc + dd) * 0.5f;
    sub[ob + 2 * pl] = (-a + bb - cc + dd) * 0.5f;
    sub[ob + 3 * pl] = ( a - bb - cc + dd) * 0.5f;
}

// ---------------- depthwise 3x3 SAME (generic, fp32 out)
__global__ void dw3x3_kernel(const float* __restrict__ src, const float* __restrict__ wt,
        const float* __restrict__ scale, const float* __restrict__ bias,
        const float* __restrict__ addb, float* __restrict__ dst,
        int C, int h, int w)
{
    int t = blockIdx.x * blockDim.x + threadIdx.x;
    int total = Bc * C * h * w;
    if (t >= total) return;
    int x = t % w; int r = t / w;
    int y = r % h; r /= h;
    int c = r % C;
    const float* sp = src + (size_t)(t - x - y * w);
    float acc = 0.f;
    #pragma unroll
    for (int u = 0; u < 3; u++) {
        int yy = y + u - 1;
        if (yy < 0 || yy >= h) continue;
        #pragma unroll
        for (int v = 0; v < 3; v++) {
            int xx = x + v - 1;
            if (xx < 0 || xx >= w) continue;
            acc += sp[yy * w + xx] * wt[(u * 3 + v) * C + c];
        }
    }
    if (bias) acc += bias[c];
    acc *= scale[c];
    if (addb) acc += addb[t];
    dst[t] = acc;
}

// ---------------- base depthwise 3x3 + bias, *scale, +recon -> bf16 NHWC (B,56,56,32)
__global__ void dwbase_kernel(const float* __restrict__ src, const float* __restrict__ wt,
        const float* __restrict__ scale, const float* __restrict__ bias,
        const float* __restrict__ addb, bf16* __restrict__ dst_nhwc)
{
    int t = blockIdx.x * blockDim.x + threadIdx.x;
    int total = Bc * 32 * Nc;
    if (t >= total) return;
    int x = t % Wcc; int r = t / Wcc;
    int y = r % Hc; r /= Hc;
    int c = r & 31; int b = r >> 5;
    const float* sp = src + (size_t)(t - x - y * Wcc);
    float acc = 0.f;
    #pragma unroll
    for (int u = 0; u < 3; u++) {
        int yy = y + u - 1;
        if (yy < 0 || yy >= Hc) continue;
        #pragma unroll
        for (int v = 0; v < 3; v++) {
            int xx = x + v - 1;
            if (xx < 0 || xx >= Wcc) continue;
            acc += sp[yy * Wcc + xx] * wt[(u * 3 + v) * 32 + c];
        }
    }
    acc = (acc + bias[c]) * scale[c] + addb[t];
    dst_nhwc[(((size_t)b * Hc + y) * Wcc + x) * 32 + c] = __float2bfloat16(acc);
}

// ---------------- Haar IDWT (+ll add, crop)
__global__ void idwt_kernel(const float* __restrict__ tl, const float* __restrict__ nxt,
        float* __restrict__ outp, int h2, int w2, int ho, int wo)
{
    int t = blockIdx.x * blockDim.x + threadIdx.x;
    int total = Bc * 32 * ho * wo;
    if (t >= total) return;
    int x = t % wo; int r = t / wo;
    int y = r % ho; r /= ho;
    int c = r & 31; int b = r >> 5;
    int y2 = y >> 1, x2 = x >> 1;
    size_t pl = (size_t)h2 * w2;
    size_t base = (size_t)(b * 128 + c * 4) * pl + y2 * w2 + x2;
    float ll = tl[base];
    if (nxt) ll += nxt[(size_t)(b * 32 + c) * pl + y2 * w2 + x2];
    float lh = tl[base + pl], hl = tl[base + 2 * pl], hh = tl[base + 3 * pl];
    float v;
    if ((y & 1) == 0) v = ((x & 1) == 0) ? (ll - lh - hl + hh) : (ll - lh + hl - hh);
    else              v = ((x & 1) == 0) ? (ll + lh - hl - hh) : (ll + lh + hl + hh);
    outp[t] = v * 0.5f;
}

// ---------------- merged weight prep: all 6 transposes + cp2d weight reorder, 1 launch
__global__ void wprep_kernel(const float* __restrict__ qw, const float* __restrict__ kv1w,
        const float* __restrict__ kv2w, const float* __restrict__ pw,
        const float* __restrict__ f1w, const float* __restrict__ f2w,
        const float* __restrict__ cpw, bf16* __restrict__ qwt, bf16* __restrict__ kv1wt,
        bf16* __restrict__ kv2wt, bf16* __restrict__ pwt, bf16* __restrict__ w1t,
        bf16* __restrict__ w2t, bf16* __restrict__ cpwt)
{
    int t = blockIdx.x * blockDim.x + threadIdx.x;
    if (t < 9216) {
        int n = t % 96, k = t / 96;
        qwt[n * 96 + k] = __float2bfloat16(qw[t]);
    } else if (t < 18432) {
        int u = t - 9216; int n = u % 96, k = u / 96;
        kv1wt[n * 96 + k] = __float2bfloat16(kv1w[u]);
    } else if (t < 27648) {
        int u = t - 18432; int n = u % 96, k = u / 96;
        kv2wt[n * 96 + k] = __float2bfloat16(kv2w[u]);
    } else if (t < 44032) {
        int u = t - 27648; int n = u % 128, k = u / 128;
        pwt[n * 128 + k] = __float2bfloat16(pw[u]);
    } else if (t < 109568) {
        int u = t - 44032; int n = u % 512, k = u / 512;
        w1t[(size_t)n * 128 + k] = __float2bfloat16(f1w[u]);
    } else if (t < 175104) {
        int u = t - 109568; int n = u % 128, k = u / 128;
        w2t[(size_t)n * 512 + k] = __float2bfloat16(f2w[u]);
    } else if (t < 184320) {
        int u = t - 175104; int co = u / 288, k = u % 288;
        cpwt[u] = __float2bfloat16(cpw[k * 32 + co]);
    }
}

// ---------------- cp2d via implicit-GEMM MFMA: src bf16 NHWC, dst fp32 NHWC
__global__ __launch_bounds__(256) void cp2d_mfma_kernel(const bf16* __restrict__ src,
        const bf16* __restrict__ wtc, const float* __restrict__ bias,
        float* __restrict__ dst)
{
    __shared__ unsigned short in_s[10 * 400];
    __shared__ unsigned short w_s[32 * 296];
    int tid = threadIdx.x;
    int b = blockIdx.y;
    int ty = blockIdx.x / 7, tx = blockIdx.x % 7;
    for (int idx = tid; idx < 1152; idx += 256) {
        int co = idx / 36, j8 = (idx % 36) * 8;
        *(int4*)&w_s[co * 296 + j8] = *(const int4*)(wtc + co * 288 + j8);
    }
    {
        int idx = tid;
        if (idx < 200) {
            int cell = idx >> 1, half = idx & 1;
            int dy = cell / 10, dx = cell % 10;
            int gy = ty * 8 - 1 + dy, gx = tx * 8 - 1 + dx;
            int4 v0 = make_int4(0, 0, 0, 0), v1 = v0;
            if (gy >= 0 && gy < 56 && gx >= 0 && gx < 56) {
                const int4* gp = (const int4*)(src + ((((size_t)b * 56 + gy) * 56 + gx) * 32 + half * 16));
                v0 = gp[0]; v1 = gp[1];
            }
            *(int4*)&in_s[dy * 400 + dx * 40 + half * 16] = v0;
            *(int4*)&in_s[dy * 400 + dx * 40 + half * 16 + 8] = v1;
        }
    }
    __syncthreads();
    int wave = tid >> 6, lane = tid & 63;
    int ml = lane & 15, qd = lane >> 4;
    int m = wave * 16 + ml;
    int ly = m >> 3, lx = m & 7;
    f32x4 acc0 = {0.f, 0.f, 0.f, 0.f}, acc1 = {0.f, 0.f, 0.f, 0.f};
    #pragma unroll
    for (int u = 0; u < 3; u++)
    #pragma unroll
    for (int v = 0; v < 3; v++) {
        bf16x8 af = *(const bf16x8*)&in_s[(ly + u) * 400 + (lx + v) * 40 + qd * 8];
        int k = (u * 3 + v) * 32 + qd * 8;
        bf16x8 b0 = *(const bf16x8*)&w_s[ml * 296 + k];
        bf16x8 b1 = *(const bf16x8*)&w_s[(16 + ml) * 296 + k];
        acc0 = __builtin_amdgcn_mfma_f32_16x16x32_bf16(af, b0, acc0, 0, 0, 0);
        acc1 = __builtin_amdgcn_mfma_f32_16x16x32_bf16(af, b1, acc1, 0, 0, 0);
    }
    float bia0 = bias[ml], bia1 = bias[16 + ml];
    #pragma unroll
    for (int r = 0; r < 4; r++) {
        int mr = wave * 16 + qd * 4 + r;
        int ry = ty * 8 + (mr >> 3), rx = tx * 8 + (mr & 7);
        float* dp = dst + (((size_t)b * 56 + ry) * 56 + rx) * 32;
        dp[ml] = acc0[r] + bia0;
        dp[16 + ml] = acc1[r] + bia1;
    }
}

// ---------------- cn: LN over 32 ch (NHWC contiguous) + gelu -> bf16 attn_cat cols 96..127
__global__ void cn_kernel(const float* __restrict__ cb, const float* __restrict__ g,
        const float* __restrict__ be, bf16* __restrict__ attn_cat)
{
    int t = blockIdx.x * blockDim.x + threadIdx.x;
    if (t >= Bc * Nc) return;
    const float* p = cb + (size_t)t * 32;
    float v[32]; float s = 0.f;
    #pragma unroll
    for (int c = 0; c < 32; c++) { v[c] = p[c]; s += v[c]; }
    float mean = s * (1.f / 32.f), q = 0.f;
    #pragma unroll
    for (int c = 0; c < 32; c++) { float d = v[c] - mean; q += d * d; }
    float inv = rsqrtf(q * (1.f / 32.f) + EPSc);
    bf16* o = attn_cat + (size_t)t * 128 + 96;
    #pragma unroll
    for (int c = 0; c < 32; c++)
        o[c] = __float2bfloat16(gelu_f((v[c] - mean) * inv * g[c] + be[c]));
}

// ---------------- sr: depthwise ks x ks stride ks VALID; out (B,L,96) fp32
__global__ void sr_kernel(const float* __restrict__ xa, const float* __restrict__ wt,
        const float* __restrict__ bias, float* __restrict__ outp, int ks, int Ld)
{
    int t = blockIdx.x * blockDim.x + threadIdx.x;
    int total = Bc * Ld * Ld * Cac;
    if (t >= total) return;
    int c = t % Cac; int r = t / Cac;
    int j = r % Ld; r /= Ld;
    int i = r % Ld; int b = r / Ld;
    float acc = bias[c];
    for (int u = 0; u < ks; u++)
        for (int v = 0; v < ks; v++)
            acc += xa[(size_t)(b * Nc + (i * ks + u) * Wcc + (j * ks + v)) * Cac + c]
                 * wt[(u * ks + v) * Cac + c];
    outp[t] = acc;
}

// ---------------- LN over 96 + gelu -> bf16
__global__ __launch_bounds__(256) void ln96_kernel(const float* __restrict__ src,
        const float* __restrict__ g, const float* __restrict__ be,
        bf16* __restrict__ dst, int R)
{
    int wv = threadIdx.x >> 6, lane = threadIdx.x & 63;
    int row = blockIdx.x * 4 + wv;
    if (row >= R) return;
    const float* sp = src + (size_t)row * 96;
    float x0 = sp[lane];
    float x1 = (lane < 32) ? sp[64 + lane] : 0.f;
    float s = x0 + x1, q = x0 * x0 + x1 * x1;
    for (int o = 32; o; o >>= 1) { s += __shfl_xor(s, o); q += __shfl_xor(q, o); }
    float mean = s * (1.f / 96.f);
    float inv = rsqrtf(q * (1.f / 96.f) - mean * mean + EPSc);
    dst[(size_t)row * 96 + lane] =
        __float2bfloat16(gelu_f((x0 - mean) * inv * g[lane] + be[lane]));
    if (lane < 32)
        dst[(size_t)row * 96 + 64 + lane] =
            __float2bfloat16(gelu_f((x1 - mean) * inv * g[64 + lane] + be[64 + lane]));
}

// ---------------- LN2: (B,N,128) fp32 -> bf16
__global__ __launch_bounds__(256) void ln2_kernel(const float* __restrict__ xres,
        const float* __restrict__ g, const float* __restrict__ be,
        bf16* __restrict__ xnb)
{
    int wv = threadIdx.x >> 6, lane = threadIdx.x & 63;
    int row = blockIdx.x * 4 + wv;
    if (row >= Bc * Nc) return;
    const float* xr = xres + (size_t)row * 128;
    float x0 = xr[lane], x1 = xr[lane + 64];
    float s = x0 + x1, q = x0 * x0 + x1 * x1;
    for (int o = 32; o; o >>= 1) { s += __shfl_xor(s, o); q += __shfl_xor(q, o); }
    float mean = s * (1.f / 128.f);
    float inv = rsqrtf(q * (1.f / 128.f) - mean * mean + EPSc);
    xnb[(size_t)row * 128 + lane] =
        __float2bfloat16((x0 - mean) * inv * g[lane] + be[lane]);
    xnb[(size_t)row * 128 + lane + 64] =
        __float2bfloat16((x1 - mean) * inv * g[lane + 64] + be[lane + 64]);
}

// ---------------- MFMA GEMM. MR = m-fragments per wave (block covers 64*MR rows).
// OMODE: 0 = fp32 row-major, 1 = bf16 row-major, 2 = fp32 head-major Q (B,8,N,12)
template<int NF, int MR, bool GELU, bool RES, int OMODE>
__global__ __launch_bounds__(256) void gemm_kernel(const bf16* __restrict__ A,
        const bf16* __restrict__ Wt, const float* __restrict__ bias,
        const float* __restrict__ res, void* __restrict__ outp,
        int M, int K, int Nt)
{
    constexpr int TN = 16 * NF;
    __shared__ unsigned short As[64 * MR][40];
    __shared__ unsigned short Bs[TN][40];
    int tid = threadIdx.x;
    int wave = tid >> 6, lane = tid & 63;
    int m0 = blockIdx.y * (64 * MR), n0 = blockIdx.x * TN;
    f32x4 acc[MR][NF];
    #pragma unroll
    for (int i = 0; i < MR; i++)
        #pragma unroll
        for (int f = 0; f < NF; f++) acc[i][f] = (f32x4){0.f, 0.f, 0.f, 0.f};

    int ar = tid >> 2, ac = (tid & 3) << 3;
    int ml = wave * 16 + (lane & 15);
    int qd = lane >> 4;

    for (int k0 = 0; k0 < K; k0 += 32) {
        #pragma unroll
        for (int i = 0; i < MR; i++) {
            int r = ar + i * 64;
            int4 av = make_int4(0, 0, 0, 0);
            if (m0 + r < M) av = *(const int4*)(A + (size_t)(m0 + r) * K + k0 + ac);
            *(int4*)&As[r][ac] = av;
        }
        for (int idx = tid; idx < TN * 4; idx += 256) {
            int br = idx >> 2, bc = (idx & 3) << 3;
            *(int4*)&Bs[br][bc] = *(const int4*)(Wt + (size_t)(n0 + br) * K + k0 + bc);
        }
        __syncthreads();
        bf16x8 af[MR];
        #pragma unroll
        for (int i = 0; i < MR; i++) af[i] = *(const bf16x8*)&As[i * 64 + ml][qd * 8];
        #pragma unroll
        for (int f = 0; f < NF; f++) {
            bf16x8 bfv = *(const bf16x8*)&Bs[f * 16 + (lane & 15)][qd * 8];
            #pragma unroll
            for (int i = 0; i < MR; i++)
                acc[i][f] = __builtin_amdgcn_mfma_f32_16x16x32_bf16(af[i], bfv, acc[i][f], 0, 0, 0);
        }
        __syncthreads();
    }
    #pragma unroll
    for (int i = 0; i < MR; i++)
    #pragma unroll
    for (int f = 0; f < NF; f++) {
        int n = n0 + f * 16 + (lane & 15);
        #pragma unroll
        for (int r = 0; r < 4; r++) {
            int m = m0 + i * 64 + wave * 16 + qd * 4 + r;
            if (m >= M) continue;
            float v = acc[i][f][r];
            if (bias) v += bias[n];
            if (GELU) v = gelu_f(v);
            if (RES)  v += res[(size_t)m * Nt + n];
            if (OMODE == 1)
                ((bf16*)outp)[(size_t)m * Nt + n] = __float2bfloat16(v);
            else if (OMODE == 2) {
                int b = m / Nc, nn = m - b * Nc;
                int h = n / 12, d = n - h * 12;
                ((float*)outp)[(((size_t)(b * 8 + h)) * Nc + nn) * 12 + d] = v;
            } else
                ((float*)outp)[(size_t)m * Nt + n] = v;
        }
    }
}

// ---------------- attention body: round-1 proven shape: fp32 K/V in LDS,
// 1 query/thread, branchless single-pass softmax (no max shift; |s| << 80).
// exp via raw v_exp_f32 (2^x), q pre-scaled by SCALE*log2(e).
template<int L>
__device__ __forceinline__ void attn_body(const float* __restrict__ qh,
        const float* __restrict__ kv, int hl, int h, int b,
        float* kb, float* vb, bf16* __restrict__ attn_cat)
{
    // stage K,V as float4s: kv row = (b*L+l)*96 + hl*12 ; v at +48 floats (=+12 float4)
    for (int idx = threadIdx.x; idx < L * 3; idx += 256) {
        int l = idx / 3, f = idx % 3;
        const float4* kp = (const float4*)(kv + (size_t)(b * L + l) * 96 + hl * 12) + f;
        float4 kk = kp[0];
        float4 vv = kp[12];
        *(float4*)&kb[l * 12 + f * 4] = kk;
        *(float4*)&vb[l * 12 + f * 4] = vv;
    }
    int n = blockIdx.x * 256 + threadIdx.x;
    bool act = (n < Nc);
    int nn = act ? n : (Nc - 1);
    // issue q loads before the barrier (independent of LDS staging)
    const float4* qp = (const float4*)(qh + (((size_t)(b * 8 + h)) * Nc + nn) * 12);
    float4 q0 = qp[0], q1 = qp[1], q2 = qp[2];
    const float PRE = SCALEc * 1.4426950408889634f;   /* scale * log2(e) */
    q0.x *= PRE; q0.y *= PRE; q0.z *= PRE; q0.w *= PRE;
    q1.x *= PRE; q1.y *= PRE; q1.z *= PRE; q1.w *= PRE;
    q2.x *= PRE; q2.y *= PRE; q2.z *= PRE; q2.w *= PRE;
    __syncthreads();

    float den = 0.f;
    float o[12];
    #pragma unroll
    for (int d = 0; d < 12; d++) o[d] = 0.f;

    #pragma unroll 4
    for (int l = 0; l < L; l++) {
        const float4 k0 = *(const float4*)&kb[l * 12];
        const float4 k1 = *(const float4*)&kb[l * 12 + 4];
        const float4 k2 = *(const float4*)&kb[l * 12 + 8];
        // 3 independent partial chains to break the 12-FMA latency chain
        float s0 = q0.x * k0.x + q0.y * k0.y + q0.z * k0.z + q0.w * k0.w;
        float s1 = q1.x * k1.x + q1.y * k1.y + q1.z * k1.z + q1.w * k1.w;
        float s2 = q2.x * k2.x + q2.y * k2.y + q2.z * k2.z + q2.w * k2.w;
        float e = fast_exp2(s0 + s1 + s2);
        den += e;
        const float4 v0 = *(const float4*)&vb[l * 12];
        const float4 v1 = *(const float4*)&vb[l * 12 + 4];
        const float4 v2 = *(const float4*)&vb[l * 12 + 8];
        o[0] += e * v0.x; o[1]  += e * v0.y; o[2]  += e * v0.z; o[3]  += e * v0.w;
        o[4] += e * v1.x; o[5]  += e * v1.y; o[6]  += e * v1.z; o[7]  += e * v1.w;
        o[8] += e * v2.x; o[9]  += e * v2.y; o[10] += e * v2.z; o[11] += e * v2.w;
    }
    if (act) {
        float rden = 1.f / den;
        bf16* op = attn_cat + (size_t)(b * Nc + n) * 128 + h * 12;
        #pragma unroll
        for (int d = 0; d < 12; d++) op[d] = __float2bfloat16(o[d] * rden);
    }
}

// ---------------- attention (both branches merged): q head-major (B,8,N,12);
// branchless softmax single pass; writes bf16 attn_cat[0:96]
__global__ __launch_bounds__(256) void attn_kernel(const float* __restrict__ qh,
        const float* __restrict__ kv1, const float* __restrict__ kv2,
        bf16* __restrict__ attn_cat)
{
    __shared__ float kb[196 * 12];
    __shared__ float vb[196 * 12];
    int h = blockIdx.y, b = blockIdx.z;
    if (h < 4) attn_body<49> (qh, kv1, h,     h, b, kb, vb, attn_cat);
    else       attn_body<196>(qh, kv2, h - 4, h, b, kb, vb, attn_cat);
}

extern "C" void kernel_launch(void* const* d_in, const int* in_sizes, int n_in,
                              void* d_out, int out_size, void* d_ws, size_t ws_size,
                              hipStream_t stream)
{
    const float* x    = (const float*)d_in[0];
    const float* ln1w = (const float*)d_in[3];
    const float* ln1b = (const float*)d_in[4];
    const float* ln2w = (const float*)d_in[5];
    const float* ln2b = (const float*)d_in[6];
    const float* qw   = (const float*)d_in[7];
    const float* kv1w = (const float*)d_in[8];
    const float* kv2w = (const float*)d_in[9];
    const float* sr1w = (const float*)d_in[10];
    const float* sr1b = (const float*)d_in[11];
    const float* sr2w = (const float*)d_in[12];
    const float* sr2b = (const float*)d_in[13];
    const float* an1w = (const float*)d_in[14];
    const float* an1b = (const float*)d_in[15];
    const float* an2w = (const float*)d_in[16];
    const float* an2b = (const float*)d_in[17];
    const float* wbw  = (const float*)d_in[18];
    const float* wbb  = (const float*)d_in[19];
    const float* wbs  = (const float*)d_in[20];
    const float* wavw = (const float*)d_in[21];
    const float* wavs = (const float*)d_in[22];
    const float* cpw  = (const float*)d_in[23];
    const float* cpb  = (const float*)d_in[24];
    const float* cnw  = (const float*)d_in[25];
    const float* cnb  = (const float*)d_in[26];
    const float* pw   = (const float*)d_in[27];
    const float* pb   = (const float*)d_in[28];
    const float* f1w  = (const float*)d_in[29];
    const float* f1b  = (const float*)d_in[30];
    const float* f2w  = (const float*)d_in[31];
    const float* f2b  = (const float*)d_in[32];
    float* dout = (float*)d_out;
    float* ws = (float*)d_ws;

    float* XA    = ws;                      // 9,633,792
    float* QB    = ws + 9633792;            // head-major Q (B,8,N,12)
    float* XRES  = ws;                      // overlay
    bf16*  XNb   = (bf16*)(ws + 12845056);
    bf16*  XAb   = (bf16*)(ws + 19267584);
    bf16*  ACATb = (bf16*)(ws + 24084480);
    float* XCI   = ws + 30507008;
    float* SUB   = ws + 33718272;
    float* TT    = ws + 38014976;
    float* RA    = ws + 42311680;
    float* RB    = ws + 45522944;
    float* X1P   = ws + 48734208;
    float* X2P   = ws + 48884736;
    bf16*  X1Bb  = (bf16*)(ws + 49486848);
    bf16*  X2Bb  = (bf16*)(ws + 49562112);
    float* KV1   = ws + 49863168;
    float* KV2   = ws + 50013696;
    bf16*  WTB   = (bf16*)(ws + 50615808);
    bf16*  qwt   = WTB;
    bf16*  kv1wt = WTB + 9216;
    bf16*  kv2wt = WTB + 18432;
    bf16*  pwt   = WTB + 27648;
    bf16*  w1t   = WTB + 44032;
    bf16*  w2t   = WTB + 109568;
    bf16*  cpwt  = WTB + 175104;
    bf16*  Hb    = (bf16*)(ws + 24084480);
    bf16*  CIMGb = (bf16*)SUB;
    float* CBUF  = TT;
    float* S0 = SUB;            float* T0 = TT;
    float* S1 = SUB + 3211264;  float* T1 = TT + 3211264;
    float* S2 = SUB + 4014080;  float* T2 = TT + 4014080;
    float* S3 = SUB + 4214784;  float* T3 = TT + 4214784;
    float* S4 = SUB + 4280320;  float* T4 = TT + 4280320;

    // 0. weight preps (single merged launch: 184320 elements)
    wprep_kernel<<<720, 256, 0, stream>>>(qw, kv1w, kv2w, pw, f1w, f2w, cpw,
                                          qwt, kv1wt, kv2wt, pwt, w1t, w2t, cpwt);

    // 1. LN1
    ln1_kernel<<<25088, 256, 0, stream>>>(x, ln1w, ln1b, XA, XAb, XCI);

    // 2. DWT cascade
    dwt_kernel<<<3136, 256, 0, stream>>>(XCI, 1, 56, 56, 28, 28, S0);
    dwt_kernel<<<784,  256, 0, stream>>>(S0, 4, 28, 28, 14, 14, S1);
    dwt_kernel<<<196,  256, 0, stream>>>(S1, 4, 14, 14, 7, 7,   S2);
    dwt_kernel<<<64,   256, 0, stream>>>(S2, 4, 7, 7,   4, 4,   S3);
    dwt_kernel<<<16,   256, 0, stream>>>(S3, 4, 4, 4,   2, 2,   S4);

    // 3. wavelet depthwise convs
    dw3x3_kernel<<<12544, 256, 0, stream>>>(S0, wavw,        wavs,       nullptr, nullptr, T0, 128, 28, 28);
    dw3x3_kernel<<<3136,  256, 0, stream>>>(S1, wavw + 1152, wavs + 128, nullptr, nullptr, T1, 128, 14, 14);
    dw3x3_kernel<<<784,   256, 0, stream>>>(S2, wavw + 2304, wavs + 256, nullptr, nullptr, T2, 128, 7, 7);
    dw3x3_kernel<<<256,   256, 0, stream>>>(S3, wavw + 3456, wavs + 384, nullptr, nullptr, T3, 128, 4, 4);
    dw3x3_kernel<<<64,    256, 0, stream>>>(S4, wavw + 4608, wavs + 512, nullptr, nullptr, T4, 128, 2, 2);

    // 4. IDWT cascade
    idwt_kernel<<<64,    256, 0, stream>>>(T4, nullptr, RA, 2, 2, 4, 4);
    idwt_kernel<<<196,   256, 0, stream>>>(T3, RA, RB, 4, 4, 7, 7);
    idwt_kernel<<<784,   256, 0, stream>>>(T2, RB, RA, 7, 7, 14, 14);
    idwt_kernel<<<3136,  256, 0, stream>>>(T1, RA, RB, 14, 14, 28, 28);
    idwt_kernel<<<12544, 256, 0, stream>>>(T0, RB, RA, 28, 28, 56, 56);

    // 5. base depthwise conv -> bf16 NHWC
    dwbase_kernel<<<12544, 256, 0, stream>>>(XCI, wbw, wbs, wbb, RA, CIMGb);

    // 6. cp2d implicit-GEMM MFMA
    cp2d_mfma_kernel<<<dim3(49, 32), 256, 0, stream>>>(CIMGb, cpwt, cpb, CBUF);

    // 7. cn -> ACATb[96:128]
    cn_kernel<<<392, 256, 0, stream>>>(CBUF, cnw, cnb, ACATb);

    // 8/9. spatial reductions
    sr_kernel<<<588,  256, 0, stream>>>(XA, sr1w, sr1b, X1P, 8, 7);
    sr_kernel<<<2352, 256, 0, stream>>>(XA, sr2w, sr2b, X2P, 4, 14);

    // 10. LN96 + gelu -> bf16
    ln96_kernel<<<392,  256, 0, stream>>>(X1P, an1w, an1b, X1Bb, 1568);
    ln96_kernel<<<1568, 256, 0, stream>>>(X2P, an2w, an2b, X2Bb, 6272);

    // 11. q / kv GEMMs (q -> head-major)
    gemm_kernel<6,2,false,false,2><<<dim3(1, 784), 256, 0, stream>>>(XAb,  qwt,   nullptr, nullptr, QB,  100352, 96, 96);
    gemm_kernel<6,1,false,false,0><<<dim3(1, 25),  256, 0, stream>>>(X1Bb, kv1wt, nullptr, nullptr, KV1, 1568,   96, 96);
    gemm_kernel<6,1,false,false,0><<<dim3(1, 98),  256, 0, stream>>>(X2Bb, kv2wt, nullptr, nullptr, KV2, 6272,   96, 96);

    // 12. merged attention -> ACATb[0:96]  (round-1 shape: 1 q/thread)
    attn_kernel<<<dim3(13, 8, 32), 256, 0, stream>>>(QB, KV1, KV2, ACATb);

    // 13. proj + bias + residual(x) -> XRES  (128x128 tile)
    gemm_kernel<8,2,false,true,0><<<dim3(1, 784), 256, 0, stream>>>(ACATb, pwt, pb, x, XRES, 100352, 128, 128);

    // 14. LN2 -> bf16
    ln2_kernel<<<25088, 256, 0, stream>>>(XRES, ln2w, ln2b, XNb);

    // 15. fc1 + bias + gelu -> Hb bf16  (128x128 tile)
    gemm_kernel<8,2,true,false,1><<<dim3(4, 784), 256, 0, stream>>>(XNb, w1t, f1b, nullptr, Hb, 100352, 128, 512);

    // 16. fc2 + bias + residual(XRES) -> d_out fp32  (128x128 tile)
    gemm_kernel<8,2,false,true,0><<<dim3(1, 784), 256, 0, stream>>>(Hb, w2t, f2b, XRES, dout, 100352, 512, 128);
}

// Round 9
// 630.374 us; speedup vs baseline: 1.3189x; 1.3189x over previous
//
#include <hip/hip_runtime.h>
#include <hip/hip_bf16.h>
#include <math.h>

typedef __hip_bfloat16 bf16;
typedef __attribute__((ext_vector_type(8))) short bf16x8;
typedef __attribute__((ext_vector_type(4))) float f32x4;

#define Bc   32
#define Hc   56
#define Wcc  56
#define Nc   3136
#define Cpc  32
#define Cac  96
#define EPSc 1e-5f
#define SCALEc 0.28867513459481287f   /* 1/sqrt(12) */

__device__ __forceinline__ float gelu_f(float x) {
    return 0.5f * x * (1.0f + erff(x * 0.7071067811865475f));
}

// raw v_exp_f32 (2^x). Fallback keeps correctness if builtin is absent.
__device__ __forceinline__ float fast_exp2(float x) {
#if defined(__has_builtin)
#if __has_builtin(__builtin_amdgcn_exp2f)
    return __builtin_amdgcn_exp2f(x);
#else
    return exp2f(x);
#endif
#else
    return exp2f(x);
#endif
}

// ---------------- LN1: (B,N,128) -> xa fp32 (B,N,96) + xab bf16 + xc_img (B,32,56,56) fp32
__global__ __launch_bounds__(256) void ln1_kernel(const float* __restrict__ x,
        const float* __restrict__ g, const float* __restrict__ be,
        float* __restrict__ xa, bf16* __restrict__ xab, float* __restrict__ xc_img)
{
    int wv = threadIdx.x >> 6, lane = threadIdx.x & 63;
    int row = blockIdx.x * 4 + wv;
    if (row >= Bc * Nc) return;
    const float* xr = x + (size_t)row * 128;
    float x0 = xr[lane];
    float x1 = xr[lane + 64];
    float s = x0 + x1, q = x0 * x0 + x1 * x1;
    for (int o = 32; o; o >>= 1) { s += __shfl_xor(s, o); q += __shfl_xor(q, o); }
    float mean = s * (1.f / 128.f);
    float inv = rsqrtf(q * (1.f / 128.f) - mean * mean + EPSc);
    int b = row / Nc, n = row % Nc;
    {
        int c = lane;
        float y = (x0 - mean) * inv * g[c] + be[c];
        if (c < Cpc) xc_img[(size_t)(b * Cpc + c) * Nc + n] = y;
        else { xa[(size_t)row * Cac + (c - Cpc)] = y;
               xab[(size_t)row * Cac + (c - Cpc)] = __float2bfloat16(y); }
    }
    {
        int c = lane + 64;
        float y = (x1 - mean) * inv * g[c] + be[c];
        xa[(size_t)row * Cac + (c - Cpc)] = y;
        xab[(size_t)row * Cac + (c - Cpc)] = __float2bfloat16(y);
    }
}

// ---------------- Haar DWT
__global__ void dwt_kernel(const float* __restrict__ src, int cs, int h, int w,
                           int h2, int w2, float* __restrict__ sub)
{
    int t = blockIdx.x * blockDim.x + threadIdx.x;
    int total = Bc * 32 * h2 * w2;
    if (t >= total) return;
    int xx = t % w2; int r = t / w2;
    int yy = r % h2; r /= h2;
    int c = r & 31; int b = r >> 5;
    const float* sp = src + (size_t)cs * (b * 32 + c) * h * w;
    int y0 = yy * 2, x0 = xx * 2;
    bool xe = (x0 + 1 < w), ye = (y0 + 1 < h);
    float a  = sp[y0 * w + x0];
    float bb = xe ? sp[y0 * w + x0 + 1] : 0.f;
    float cc = ye ? sp[(y0 + 1) * w + x0] : 0.f;
    float dd = (xe && ye) ? sp[(y0 + 1) * w + x0 + 1] : 0.f;
    size_t pl = (size_t)h2 * w2;
    size_t ob = (size_t)(b * 128 + c * 4) * pl + yy * w2 + xx;
    sub[ob]          = ( a + bb + cc + dd) * 0.5f;
    sub[ob + pl]     = (-a - bb + cc + dd) * 0.5f;
    sub[ob + 2 * pl] = (-a + bb - cc + dd) * 0.5f;
    sub[ob + 3 * pl] = ( a - bb - cc + dd) * 0.5f;
}

// ---------------- merged wavelet depthwise 3x3 (all 5 levels, one launch)
template<int H>
__device__ __forceinline__ void dw3_body(int r, const float* __restrict__ src,
        const float* __restrict__ wt, const float* __restrict__ scale,
        float* __restrict__ dst)
{
    int x = r % H; int rr = r / H;
    int y = rr % H; rr /= H;
    int c = rr & 127;
    const float* sp = src + (r - x - y * H);
    float acc = 0.f;
    #pragma unroll
    for (int u = 0; u < 3; u++) {
        int yy = y + u - 1;
        if (yy < 0 || yy >= H) continue;
        #pragma unroll
        for (int v = 0; v < 3; v++) {
            int xx = x + v - 1;
            if (xx < 0 || xx >= H) continue;
            acc += sp[yy * H + xx] * wt[(u * 3 + v) * 128 + c];
        }
    }
    dst[r] = acc * scale[c];
}

__global__ void dw3x3_all_kernel(const float* __restrict__ sub, const float* __restrict__ wavw,
        const float* __restrict__ wavs, float* __restrict__ tt)
{
    int t = blockIdx.x * blockDim.x + threadIdx.x;
    if (t < 3211264)      dw3_body<28>(t,           sub,           wavw,        wavs,       tt);
    else if (t < 4014080) dw3_body<14>(t - 3211264, sub + 3211264, wavw + 1152, wavs + 128, tt + 3211264);
    else if (t < 4214784) dw3_body<7> (t - 4014080, sub + 4014080, wavw + 2304, wavs + 256, tt + 4014080);
    else if (t < 4280320) dw3_body<4> (t - 4214784, sub + 4214784, wavw + 3456, wavs + 384, tt + 4214784);
    else if (t < 4296704) dw3_body<2> (t - 4280320, sub + 4280320, wavw + 4608, wavs + 512, tt + 4280320);
}

// ---------------- Haar IDWT (+ll add, crop) — levels 4..1
__global__ void idwt_kernel(const float* __restrict__ tl, const float* __restrict__ nxt,
        float* __restrict__ outp, int h2, int w2, int ho, int wo)
{
    int t = blockIdx.x * blockDim.x + threadIdx.x;
    int total = Bc * 32 * ho * wo;
    if (t >= total) return;
    int x = t % wo; int r = t / wo;
    int y = r % ho; r /= ho;
    int c = r & 31; int b = r >> 5;
    int y2 = y >> 1, x2 = x >> 1;
    size_t pl = (size_t)h2 * w2;
    size_t base = (size_t)(b * 128 + c * 4) * pl + y2 * w2 + x2;
    float ll = tl[base];
    if (nxt) ll += nxt[(size_t)(b * 32 + c) * pl + y2 * w2 + x2];
    float lh = tl[base + pl], hl = tl[base + 2 * pl], hh = tl[base + 3 * pl];
    float v;
    if ((y & 1) == 0) v = ((x & 1) == 0) ? (ll - lh - hl + hh) : (ll - lh + hl - hh);
    else              v = ((x & 1) == 0) ? (ll + lh - hl - hh) : (ll + lh + hl + hh);
    outp[t] = v * 0.5f;
}

// ---------------- fused idwt level-0 + base depthwise conv -> bf16 NHWC
// recon computed inline from T0/RB (no RA round-trip)
__global__ void idwt_dwbase_kernel(const float* __restrict__ tl, const float* __restrict__ nxt,
        const float* __restrict__ src, const float* __restrict__ wt,
        const float* __restrict__ scale, const float* __restrict__ bias,
        bf16* __restrict__ dst_nhwc)
{
    int t = blockIdx.x * blockDim.x + threadIdx.x;
    if (t >= Bc * 32 * Nc) return;
    int x = t % Wcc; int r = t / Wcc;
    int y = r % Hc; r /= Hc;
    int c = r & 31; int b = r >> 5;
    // idwt from 28x28 wavelet planes
    int y2 = y >> 1, x2 = x >> 1;
    const size_t pl = 784;
    size_t base = (size_t)(b * 128 + c * 4) * pl + y2 * 28 + x2;
    float ll = tl[base] + nxt[(size_t)(b * 32 + c) * pl + y2 * 28 + x2];
    float lh = tl[base + pl], hl = tl[base + 2 * pl], hh = tl[base + 3 * pl];
    float v;
    if ((y & 1) == 0) v = ((x & 1) == 0) ? (ll - lh - hl + hh) : (ll - lh + hl - hh);
    else              v = ((x & 1) == 0) ? (ll + lh - hl - hh) : (ll + lh + hl + hh);
    float recon = v * 0.5f;
    // base 3x3 depthwise on XCI
    const float* sp = src + (t - x - y * Wcc);
    float acc = 0.f;
    #pragma unroll
    for (int u = 0; u < 3; u++) {
        int yy = y + u - 1;
        if (yy < 0 || yy >= Hc) continue;
        #pragma unroll
        for (int vv2 = 0; vv2 < 3; vv2++) {
            int xx = x + vv2 - 1;
            if (xx < 0 || xx >= Wcc) continue;
            acc += sp[yy * Wcc + xx] * wt[(u * 3 + vv2) * 32 + c];
        }
    }
    acc = (acc + bias[c]) * scale[c] + recon;
    dst_nhwc[(((size_t)b * Hc + y) * Wcc + x) * 32 + c] = __float2bfloat16(acc);
}

// ---------------- merged weight prep: all 6 transposes + cp2d weight reorder, 1 launch
__global__ void wprep_kernel(const float* __restrict__ qw, const float* __restrict__ kv1w,
        const float* __restrict__ kv2w, const float* __restrict__ pw,
        const float* __restrict__ f1w, const float* __restrict__ f2w,
        const float* __restrict__ cpw, bf16* __restrict__ qwt, bf16* __restrict__ kv1wt,
        bf16* __restrict__ kv2wt, bf16* __restrict__ pwt, bf16* __restrict__ w1t,
        bf16* __restrict__ w2t, bf16* __restrict__ cpwt)
{
    int t = blockIdx.x * blockDim.x + threadIdx.x;
    if (t < 9216) {
        int n = t % 96, k = t / 96;
        qwt[n * 96 + k] = __float2bfloat16(qw[t]);
    } else if (t < 18432) {
        int u = t - 9216; int n = u % 96, k = u / 96;
        kv1wt[n * 96 + k] = __float2bfloat16(kv1w[u]);
    } else if (t < 27648) {
        int u = t - 18432; int n = u % 96, k = u / 96;
        kv2wt[n * 96 + k] = __float2bfloat16(kv2w[u]);
    } else if (t < 44032) {
        int u = t - 27648; int n = u % 128, k = u / 128;
        pwt[n * 128 + k] = __float2bfloat16(pw[u]);
    } else if (t < 109568) {
        int u = t - 44032; int n = u % 512, k = u / 512;
        w1t[(size_t)n * 128 + k] = __float2bfloat16(f1w[u]);
    } else if (t < 175104) {
        int u = t - 109568; int n = u % 128, k = u / 128;
        w2t[(size_t)n * 512 + k] = __float2bfloat16(f2w[u]);
    } else if (t < 184320) {
        int u = t - 175104; int co = u / 288, k = u % 288;
        cpwt[u] = __float2bfloat16(cpw[k * 32 + co]);
    }
}

// ---------------- cp2d implicit-GEMM MFMA + FUSED cn (LN over 32 ch + gelu)
// writes bf16 attn_cat cols 96..127 directly; CBUF eliminated.
__global__ __launch_bounds__(256) void cp2d_cn_kernel(const bf16* __restrict__ src,
        const bf16* __restrict__ wtc, const float* __restrict__ bias,
        const float* __restrict__ cnw, const float* __restrict__ cnb,
        bf16* __restrict__ attn_cat)
{
    __shared__ unsigned short in_s[10 * 400];
    __shared__ unsigned short w_s[32 * 296];
    int tid = threadIdx.x;
    int b = blockIdx.y;
    int ty = blockIdx.x / 7, tx = blockIdx.x % 7;
    for (int idx = tid; idx < 1152; idx += 256) {
        int co = idx / 36, j8 = (idx % 36) * 8;
        *(int4*)&w_s[co * 296 + j8] = *(const int4*)(wtc + co * 288 + j8);
    }
    {
        int idx = tid;
        if (idx < 200) {
            int cell = idx >> 1, half = idx & 1;
            int dy = cell / 10, dx = cell % 10;
            int gy = ty * 8 - 1 + dy, gx = tx * 8 - 1 + dx;
            int4 v0 = make_int4(0, 0, 0, 0), v1 = v0;
            if (gy >= 0 && gy < 56 && gx >= 0 && gx < 56) {
                const int4* gp = (const int4*)(src + ((((size_t)b * 56 + gy) * 56 + gx) * 32 + half * 16));
                v0 = gp[0]; v1 = gp[1];
            }
            *(int4*)&in_s[dy * 400 + dx * 40 + half * 16] = v0;
            *(int4*)&in_s[dy * 400 + dx * 40 + half * 16 + 8] = v1;
        }
    }
    __syncthreads();
    int wave = tid >> 6, lane = tid & 63;
    int ml = lane & 15, qd = lane >> 4;
    int m = wave * 16 + ml;
    int ly = m >> 3, lx = m & 7;
    f32x4 acc0 = {0.f, 0.f, 0.f, 0.f}, acc1 = {0.f, 0.f, 0.f, 0.f};
    #pragma unroll
    for (int u = 0; u < 3; u++)
    #pragma unroll
    for (int v = 0; v < 3; v++) {
        bf16x8 af = *(const bf16x8*)&in_s[(ly + u) * 400 + (lx + v) * 40 + qd * 8];
        int k = (u * 3 + v) * 32 + qd * 8;
        bf16x8 b0 = *(const bf16x8*)&w_s[ml * 296 + k];
        bf16x8 b1 = *(const bf16x8*)&w_s[(16 + ml) * 296 + k];
        acc0 = __builtin_amdgcn_mfma_f32_16x16x32_bf16(af, b0, acc0, 0, 0, 0);
        acc1 = __builtin_amdgcn_mfma_f32_16x16x32_bf16(af, b1, acc1, 0, 0, 0);
    }
    float bia0 = bias[ml], bia1 = bias[16 + ml];
    float g0 = cnw[ml], g1 = cnw[16 + ml];
    float be0 = cnb[ml], be1 = cnb[16 + ml];
    #pragma unroll
    for (int r = 0; r < 4; r++) {
        float c0 = acc0[r] + bia0;
        float c1 = acc1[r] + bia1;
        // LN over the 32 channels of this pixel: channels live across the 16
        // lanes (ml) of this quad-row group; xor bits 0-3 stay in-group.
        float s = c0 + c1, q = c0 * c0 + c1 * c1;
        #pragma unroll
        for (int o = 8; o; o >>= 1) { s += __shfl_xor(s, o); q += __shfl_xor(q, o); }
        float mean = s * (1.f / 32.f);
        float inv = rsqrtf(q * (1.f / 32.f) - mean * mean + EPSc);
        int mr = wave * 16 + qd * 4 + r;
        int ry = ty * 8 + (mr >> 3), rx = tx * 8 + (mr & 7);
        bf16* op = attn_cat + ((size_t)b * Nc + ry * 56 + rx) * 128 + 96;
        op[ml]      = __float2bfloat16(gelu_f((c0 - mean) * inv * g0 + be0));
        op[16 + ml] = __float2bfloat16(gelu_f((c1 - mean) * inv * g1 + be1));
    }
}

// ---------------- merged sr: both depthwise reductions in one launch
template<int KS, int LD>
__device__ __forceinline__ void sr_body(int t, const float* __restrict__ xa,
        const float* __restrict__ wt, const float* __restrict__ bias,
        float* __restrict__ outp)
{
    int c = t % Cac; int r = t / Cac;
    int j = r % LD; r /= LD;
    int i = r % LD; int b = r / LD;
    float acc = bias[c];
    for (int u = 0; u < KS; u++)
        for (int v = 0; v < KS; v++)
            acc += xa[(size_t)(b * Nc + (i * KS + u) * Wcc + (j * KS + v)) * Cac + c]
                 * wt[(u * KS + v) * Cac + c];
    outp[t] = acc;
}

__global__ void sr_all_kernel(const float* __restrict__ xa,
        const float* __restrict__ sr1w, const float* __restrict__ sr1b, float* __restrict__ x1p,
        const float* __restrict__ sr2w, const float* __restrict__ sr2b, float* __restrict__ x2p)
{
    int t = blockIdx.x * blockDim.x + threadIdx.x;
    if (t < 150528) sr_body<8, 7>(t, xa, sr1w, sr1b, x1p);
    else {
        int u = t - 150528;
        if (u < 602112) sr_body<4, 14>(u, xa, sr2w, sr2b, x2p);
    }
}

// ---------------- merged LN over 96 + gelu -> bf16 (both branches, one launch)
__global__ __launch_bounds__(256) void ln96_all_kernel(
        const float* __restrict__ s1, const float* __restrict__ g1,
        const float* __restrict__ b1, bf16* __restrict__ d1,
        const float* __restrict__ s2, const float* __restrict__ g2,
        const float* __restrict__ b2, bf16* __restrict__ d2)
{
    int wv = threadIdx.x >> 6, lane = threadIdx.x & 63;
    int row = blockIdx.x * 4 + wv;
    const float* sp; const float* g; const float* be; bf16* dst; int r;
    if (row < 1568)      { sp = s1; g = g1; be = b1; dst = d1; r = row; }
    else if (row < 7840) { sp = s2; g = g2; be = b2; dst = d2; r = row - 1568; }
    else return;
    sp += (size_t)r * 96;
    float x0 = sp[lane];
    float x1 = (lane < 32) ? sp[64 + lane] : 0.f;
    float s = x0 + x1, q = x0 * x0 + x1 * x1;
    for (int o = 32; o; o >>= 1) { s += __shfl_xor(s, o); q += __shfl_xor(q, o); }
    float mean = s * (1.f / 96.f);
    float inv = rsqrtf(q * (1.f / 96.f) - mean * mean + EPSc);
    dst[(size_t)r * 96 + lane] =
        __float2bfloat16(gelu_f((x0 - mean) * inv * g[lane] + be[lane]));
    if (lane < 32)
        dst[(size_t)r * 96 + 64 + lane] =
            __float2bfloat16(gelu_f((x1 - mean) * inv * g[64 + lane] + be[64 + lane]));
}

// ---------------- LN2: (B,N,128) fp32 -> bf16
__global__ __launch_bounds__(256) void ln2_kernel(const float* __restrict__ xres,
        const float* __restrict__ g, const float* __restrict__ be,
        bf16* __restrict__ xnb)
{
    int wv = threadIdx.x >> 6, lane = threadIdx.x & 63;
    int row = blockIdx.x * 4 + wv;
    if (row >= Bc * Nc) return;
    const float* xr = xres + (size_t)row * 128;
    float x0 = xr[lane], x1 = xr[lane + 64];
    float s = x0 + x1, q = x0 * x0 + x1 * x1;
    for (int o = 32; o; o >>= 1) { s += __shfl_xor(s, o); q += __shfl_xor(q, o); }
    float mean = s * (1.f / 128.f);
    float inv = rsqrtf(q * (1.f / 128.f) - mean * mean + EPSc);
    xnb[(size_t)row * 128 + lane] =
        __float2bfloat16((x0 - mean) * inv * g[lane] + be[lane]);
    xnb[(size_t)row * 128 + lane + 64] =
        __float2bfloat16((x1 - mean) * inv * g[lane + 64] + be[lane + 64]);
}

// ---------------- MFMA GEMM (round-1 proven shape: MR=1). OMODE: 0 = fp32
// row-major, 1 = bf16 row-major, 2 = fp32 head-major Q layout (B,8,N,12)
template<int NF, bool GELU, bool RES, int OMODE>
__global__ __launch_bounds__(256) void gemm_kernel(const bf16* __restrict__ A,
        const bf16* __restrict__ Wt, const float* __restrict__ bias,
        const float* __restrict__ res, void* __restrict__ outp,
        int M, int K, int Nt)
{
    constexpr int TN = 16 * NF;
    __shared__ unsigned short As[64][40];
    __shared__ unsigned short Bs[TN][40];
    int tid = threadIdx.x;
    int wave = tid >> 6, lane = tid & 63;
    int m0 = blockIdx.y * 64, n0 = blockIdx.x * TN;
    f32x4 acc[NF];
    #pragma unroll
    for (int f = 0; f < NF; f++) acc[f] = (f32x4){0.f, 0.f, 0.f, 0.f};

    int ar = tid >> 2, ac = (tid & 3) << 3;
    int ml = wave * 16 + (lane & 15);
    int qd = lane >> 4;

    for (int k0 = 0; k0 < K; k0 += 32) {
        int4 av = make_int4(0, 0, 0, 0);
        if (m0 + ar < M) av = *(const int4*)(A + (size_t)(m0 + ar) * K + k0 + ac);
        *(int4*)&As[ar][ac] = av;
        for (int idx = tid; idx < TN * 4; idx += 256) {
            int br = idx >> 2, bc = (idx & 3) << 3;
            *(int4*)&Bs[br][bc] = *(const int4*)(Wt + (size_t)(n0 + br) * K + k0 + bc);
        }
        __syncthreads();
        bf16x8 af = *(const bf16x8*)&As[ml][qd * 8];
        #pragma unroll
        for (int f = 0; f < NF; f++) {
            bf16x8 bfv = *(const bf16x8*)&Bs[f * 16 + (lane & 15)][qd * 8];
            acc[f] = __builtin_amdgcn_mfma_f32_16x16x32_bf16(af, bfv, acc[f], 0, 0, 0);
        }
        __syncthreads();
    }
    #pragma unroll
    for (int f = 0; f < NF; f++) {
        int n = n0 + f * 16 + (lane & 15);
        #pragma unroll
        for (int r = 0; r < 4; r++) {
            int m = m0 + wave * 16 + qd * 4 + r;
            if (m >= M) continue;
            float v = acc[f][r];
            if (bias) v += bias[n];
            if (GELU) v = gelu_f(v);
            if (RES)  v += res[(size_t)m * Nt + n];
            if (OMODE == 1)
                ((bf16*)outp)[(size_t)m * Nt + n] = __float2bfloat16(v);
            else if (OMODE == 2) {
                int b = m / Nc, nn = m - b * Nc;
                int h = n / 12, d = n - h * 12;
                ((float*)outp)[(((size_t)(b * 8 + h)) * Nc + nn) * 12 + d] = v;
            } else
                ((float*)outp)[(size_t)m * Nt + n] = v;
        }
    }
}

// ---------------- attention body: round-1 proven shape + raw v_exp_f32 (125us):
// fp32 K/V in LDS, 1 query/thread, branchless single-pass softmax.
template<int L>
__device__ __forceinline__ void attn_body(const float* __restrict__ qh,
        const float* __restrict__ kv, int hl, int h, int b,
        float* kb, float* vb, bf16* __restrict__ attn_cat)
{
    // stage K,V as float4s: kv row = (b*L+l)*96 + hl*12 ; v at +48 floats (=+12 float4)
    for (int idx = threadIdx.x; idx < L * 3; idx += 256) {
        int l = idx / 3, f = idx % 3;
        const float4* kp = (const float4*)(kv + (size_t)(b * L + l) * 96 + hl * 12) + f;
        float4 kk = kp[0];
        float4 vv = kp[12];
        *(float4*)&kb[l * 12 + f * 4] = kk;
        *(float4*)&vb[l * 12 + f * 4] = vv;
    }
    int n = blockIdx.x * 256 + threadIdx.x;
    bool act = (n < Nc);
    int nn = act ? n : (Nc - 1);
    const float4* qp = (const float4*)(qh + (((size_t)(b * 8 + h)) * Nc + nn) * 12);
    float4 q0 = qp[0], q1 = qp[1], q2 = qp[2];
    const float PRE = SCALEc * 1.4426950408889634f;   /* scale * log2(e) */
    q0.x *= PRE; q0.y *= PRE; q0.z *= PRE; q0.w *= PRE;
    q1.x *= PRE; q1.y *= PRE; q1.z *= PRE; q1.w *= PRE;
    q2.x *= PRE; q2.y *= PRE; q2.z *= PRE; q2.w *= PRE;
    __syncthreads();

    float den = 0.f;
    float o[12];
    #pragma unroll
    for (int d = 0; d < 12; d++) o[d] = 0.f;

    #pragma unroll 4
    for (int l = 0; l < L; l++) {
        const float4 k0 = *(const float4*)&kb[l * 12];
        const float4 k1 = *(const float4*)&kb[l * 12 + 4];
        const float4 k2 = *(const float4*)&kb[l * 12 + 8];
        float s0 = q0.x * k0.x + q0.y * k0.y + q0.z * k0.z + q0.w * k0.w;
        float s1 = q1.x * k1.x + q1.y * k1.y + q1.z * k1.z + q1.w * k1.w;
        float s2 = q2.x * k2.x + q2.y * k2.y + q2.z * k2.z + q2.w * k2.w;
        float e = fast_exp2(s0 + s1 + s2);
        den += e;
        const float4 v0 = *(const float4*)&vb[l * 12];
        const float4 v1 = *(const float4*)&vb[l * 12 + 4];
        const float4 v2 = *(const float4*)&vb[l * 12 + 8];
        o[0] += e * v0.x; o[1]  += e * v0.y; o[2]  += e * v0.z; o[3]  += e * v0.w;
        o[4] += e * v1.x; o[5]  += e * v1.y; o[6]  += e * v1.z; o[7]  += e * v1.w;
        o[8] += e * v2.x; o[9]  += e * v2.y; o[10] += e * v2.z; o[11] += e * v2.w;
    }
    if (act) {
        float rden = 1.f / den;
        bf16* op = attn_cat + (size_t)(b * Nc + n) * 128 + h * 12;
        #pragma unroll
        for (int d = 0; d < 12; d++) op[d] = __float2bfloat16(o[d] * rden);
    }
}

__global__ __launch_bounds__(256) void attn_kernel(const float* __restrict__ qh,
        const float* __restrict__ kv1, const float* __restrict__ kv2,
        bf16* __restrict__ attn_cat)
{
    __shared__ float kb[196 * 12];
    __shared__ float vb[196 * 12];
    int h = blockIdx.y, b = blockIdx.z;
    if (h < 4) attn_body<49> (qh, kv1, h,     h, b, kb, vb, attn_cat);
    else       attn_body<196>(qh, kv2, h - 4, h, b, kb, vb, attn_cat);
}

extern "C" void kernel_launch(void* const* d_in, const int* in_sizes, int n_in,
                              void* d_out, int out_size, void* d_ws, size_t ws_size,
                              hipStream_t stream)
{
    const float* x    = (const float*)d_in[0];
    const float* ln1w = (const float*)d_in[3];
    const float* ln1b = (const float*)d_in[4];
    const float* ln2w = (const float*)d_in[5];
    const float* ln2b = (const float*)d_in[6];
    const float* qw   = (const float*)d_in[7];
    const float* kv1w = (const float*)d_in[8];
    const float* kv2w = (const float*)d_in[9];
    const float* sr1w = (const float*)d_in[10];
    const float* sr1b = (const float*)d_in[11];
    const float* sr2w = (const float*)d_in[12];
    const float* sr2b = (const float*)d_in[13];
    const float* an1w = (const float*)d_in[14];
    const float* an1b = (const float*)d_in[15];
    const float* an2w = (const float*)d_in[16];
    const float* an2b = (const float*)d_in[17];
    const float* wbw  = (const float*)d_in[18];
    const float* wbb  = (const float*)d_in[19];
    const float* wbs  = (const float*)d_in[20];
    const float* wavw = (const float*)d_in[21];
    const float* wavs = (const float*)d_in[22];
    const float* cpw  = (const float*)d_in[23];
    const float* cpb  = (const float*)d_in[24];
    const float* cnw  = (const float*)d_in[25];
    const float* cnb  = (const float*)d_in[26];
    const float* pw   = (const float*)d_in[27];
    const float* pb   = (const float*)d_in[28];
    const float* f1w  = (const float*)d_in[29];
    const float* f1b  = (const float*)d_in[30];
    const float* f2w  = (const float*)d_in[31];
    const float* f2b  = (const float*)d_in[32];
    float* dout = (float*)d_out;
    float* ws = (float*)d_ws;

    float* XA    = ws;                      // 9,633,792
    float* QB    = ws + 9633792;            // head-major Q (B,8,N,12)
    float* XRES  = ws;                      // overlay
    bf16*  XNb   = (bf16*)(ws + 12845056);
    bf16*  XAb   = (bf16*)(ws + 19267584);
    bf16*  ACATb = (bf16*)(ws + 24084480);
    float* XCI   = ws + 30507008;
    float* SUB   = ws + 33718272;
    float* TT    = ws + 38014976;
    float* RA    = ws + 42311680;
    float* RB    = ws + 45522944;
    float* X1P   = ws + 48734208;
    float* X2P   = ws + 48884736;
    bf16*  X1Bb  = (bf16*)(ws + 49486848);
    bf16*  X2Bb  = (bf16*)(ws + 49562112);
    float* KV1   = ws + 49863168;
    float* KV2   = ws + 50013696;
    bf16*  WTB   = (bf16*)(ws + 50615808);
    bf16*  qwt   = WTB;
    bf16*  kv1wt = WTB + 9216;
    bf16*  kv2wt = WTB + 18432;
    bf16*  pwt   = WTB + 27648;
    bf16*  w1t   = WTB + 44032;
    bf16*  w2t   = WTB + 109568;
    bf16*  cpwt  = WTB + 175104;
    bf16*  Hb    = (bf16*)(ws + 24084480);
    bf16*  CIMGb = (bf16*)SUB;
    float* S0 = SUB;            float* T0 = TT;
    float* S1 = SUB + 3211264;  float* T1 = TT + 3211264;
    float* S2 = SUB + 4014080;  float* T2 = TT + 4014080;
    float* S3 = SUB + 4214784;  float* T3 = TT + 4214784;
    float* S4 = SUB + 4280320;  float* T4 = TT + 4280320;

    // 0. weight preps (single merged launch)
    wprep_kernel<<<720, 256, 0, stream>>>(qw, kv1w, kv2w, pw, f1w, f2w, cpw,
                                          qwt, kv1wt, kv2wt, pwt, w1t, w2t, cpwt);

    // 1. LN1
    ln1_kernel<<<25088, 256, 0, stream>>>(x, ln1w, ln1b, XA, XAb, XCI);

    // 2. DWT cascade (sequential on LL)
    dwt_kernel<<<3136, 256, 0, stream>>>(XCI, 1, 56, 56, 28, 28, S0);
    dwt_kernel<<<784,  256, 0, stream>>>(S0, 4, 28, 28, 14, 14, S1);
    dwt_kernel<<<196,  256, 0, stream>>>(S1, 4, 14, 14, 7, 7,   S2);
    dwt_kernel<<<64,   256, 0, stream>>>(S2, 4, 7, 7,   4, 4,   S3);
    dwt_kernel<<<16,   256, 0, stream>>>(S3, 4, 4, 4,   2, 2,   S4);

    // 3. ALL wavelet depthwise convs in one launch (levels independent)
    dw3x3_all_kernel<<<16784, 256, 0, stream>>>(SUB, wavw, wavs, TT);

    // 4. IDWT cascade levels 4..1
    idwt_kernel<<<64,   256, 0, stream>>>(T4, nullptr, RA, 2, 2, 4, 4);
    idwt_kernel<<<196,  256, 0, stream>>>(T3, RA, RB, 4, 4, 7, 7);
    idwt_kernel<<<784,  256, 0, stream>>>(T2, RB, RA, 7, 7, 14, 14);
    idwt_kernel<<<3136, 256, 0, stream>>>(T1, RA, RB, 14, 14, 28, 28);

    // 5. fused idwt level-0 + base depthwise conv -> bf16 NHWC
    idwt_dwbase_kernel<<<12544, 256, 0, stream>>>(T0, RB, XCI, wbw, wbs, wbb, CIMGb);

    // 6. cp2d implicit-GEMM MFMA + fused cn -> ACATb[96:128]
    cp2d_cn_kernel<<<dim3(49, 32), 256, 0, stream>>>(CIMGb, cpwt, cpb, cnw, cnb, ACATb);

    // 7. merged spatial reductions
    sr_all_kernel<<<2940, 256, 0, stream>>>(XA, sr1w, sr1b, X1P, sr2w, sr2b, X2P);

    // 8. merged LN96 + gelu -> bf16
    ln96_all_kernel<<<1960, 256, 0, stream>>>(X1P, an1w, an1b, X1Bb,
                                              X2P, an2w, an2b, X2Bb);

    // 9. q / kv GEMMs (q -> head-major); round-1 proven shapes
    gemm_kernel<6,false,false,2><<<dim3(1, 1568), 256, 0, stream>>>(XAb,  qwt,   nullptr, nullptr, QB,  100352, 96, 96);
    gemm_kernel<6,false,false,0><<<dim3(1, 25),   256, 0, stream>>>(X1Bb, kv1wt, nullptr, nullptr, KV1, 1568,   96, 96);
    gemm_kernel<6,false,false,0><<<dim3(1, 98),   256, 0, stream>>>(X2Bb, kv2wt, nullptr, nullptr, KV2, 6272,   96, 96);

    // 10. merged attention -> ACATb[0:96]
    attn_kernel<<<dim3(13, 8, 32), 256, 0, stream>>>(QB, KV1, KV2, ACATb);

    // 11. proj + bias + residual(x) -> XRES
    gemm_kernel<4,false,true,0><<<dim3(2, 1568), 256, 0, stream>>>(ACATb, pwt, pb, x, XRES, 100352, 128, 128);

    // 12. LN2 -> bf16
    ln2_kernel<<<25088, 256, 0, stream>>>(XRES, ln2w, ln2b, XNb);

    // 13. fc1 + bias + gelu -> Hb bf16
    gemm_kernel<4,true,false,1><<<dim3(8, 1568), 256, 0, stream>>>(XNb, w1t, f1b, nullptr, Hb, 100352, 128, 512);

    // 14. fc2 + bias + residual(XRES) -> d_out fp32
    gemm_kernel<4,false,true,0><<<dim3(2, 1568), 256, 0, stream>>>(Hb, w2t, f2b, XRES, dout, 100352, 512, 128);
}

// Round 10
// 607.325 us; speedup vs baseline: 1.3689x; 1.0380x over previous
//
#include <hip/hip_runtime.h>
#include <hip/hip_bf16.h>
#include <math.h>

typedef __hip_bfloat16 bf16;
typedef __attribute__((ext_vector_type(8))) short bf16x8;
typedef __attribute__((ext_vector_type(4))) float f32x4;

#define Bc   32
#define Hc   56
#define Wcc  56
#define Nc   3136
#define Cpc  32
#define Cac  96
#define EPSc 1e-5f
#define SCALEc 0.28867513459481287f   /* 1/sqrt(12) */

__device__ __forceinline__ float gelu_f(float x) {
    return 0.5f * x * (1.0f + erff(x * 0.7071067811865475f));
}

// raw v_exp_f32 (2^x). Fallback keeps correctness if builtin is absent.
__device__ __forceinline__ float fast_exp2(float x) {
#if defined(__has_builtin)
#if __has_builtin(__builtin_amdgcn_exp2f)
    return __builtin_amdgcn_exp2f(x);
#else
    return exp2f(x);
#endif
#else
    return exp2f(x);
#endif
}

// ---------------- LN1: (B,N,128) -> xa fp32 (B,N,96) + xab bf16 + xc_img (B,32,56,56) fp32
__global__ __launch_bounds__(256) void ln1_kernel(const float* __restrict__ x,
        const float* __restrict__ g, const float* __restrict__ be,
        float* __restrict__ xa, bf16* __restrict__ xab, float* __restrict__ xc_img)
{
    int wv = threadIdx.x >> 6, lane = threadIdx.x & 63;
    int row = blockIdx.x * 4 + wv;
    if (row >= Bc * Nc) return;
    const float* xr = x + (size_t)row * 128;
    float x0 = xr[lane];
    float x1 = xr[lane + 64];
    float s = x0 + x1, q = x0 * x0 + x1 * x1;
    for (int o = 32; o; o >>= 1) { s += __shfl_xor(s, o); q += __shfl_xor(q, o); }
    float mean = s * (1.f / 128.f);
    float inv = rsqrtf(q * (1.f / 128.f) - mean * mean + EPSc);
    int b = row / Nc, n = row % Nc;
    {
        int c = lane;
        float y = (x0 - mean) * inv * g[c] + be[c];
        if (c < Cpc) xc_img[(size_t)(b * Cpc + c) * Nc + n] = y;
        else { xa[(size_t)row * Cac + (c - Cpc)] = y;
               xab[(size_t)row * Cac + (c - Cpc)] = __float2bfloat16(y); }
    }
    {
        int c = lane + 64;
        float y = (x1 - mean) * inv * g[c] + be[c];
        xa[(size_t)row * Cac + (c - Cpc)] = y;
        xab[(size_t)row * Cac + (c - Cpc)] = __float2bfloat16(y);
    }
}

// ---------------- Haar DWT
__global__ void dwt_kernel(const float* __restrict__ src, int cs, int h, int w,
                           int h2, int w2, float* __restrict__ sub)
{
    int t = blockIdx.x * blockDim.x + threadIdx.x;
    int total = Bc * 32 * h2 * w2;
    if (t >= total) return;
    int xx = t % w2; int r = t / w2;
    int yy = r % h2; r /= h2;
    int c = r & 31; int b = r >> 5;
    const float* sp = src + (size_t)cs * (b * 32 + c) * h * w;
    int y0 = yy * 2, x0 = xx * 2;
    bool xe = (x0 + 1 < w), ye = (y0 + 1 < h);
    float a  = sp[y0 * w + x0];
    float bb = xe ? sp[y0 * w + x0 + 1] : 0.f;
    float cc = ye ? sp[(y0 + 1) * w + x0] : 0.f;
    float dd = (xe && ye) ? sp[(y0 + 1) * w + x0 + 1] : 0.f;
    size_t pl = (size_t)h2 * w2;
    size_t ob = (size_t)(b * 128 + c * 4) * pl + yy * w2 + xx;
    sub[ob]          = ( a + bb + cc + dd) * 0.5f;
    sub[ob + pl]     = (-a - bb + cc + dd) * 0.5f;
    sub[ob + 2 * pl] = (-a + bb - cc + dd) * 0.5f;
    sub[ob + 3 * pl] = ( a - bb - cc + dd) * 0.5f;
}

// ---------------- merged wavelet depthwise 3x3 (all 5 levels, one launch)
template<int H>
__device__ __forceinline__ void dw3_body(int r, const float* __restrict__ src,
        const float* __restrict__ wt, const float* __restrict__ scale,
        float* __restrict__ dst)
{
    int x = r % H; int rr = r / H;
    int y = rr % H; rr /= H;
    int c = rr & 127;
    const float* sp = src + (r - x - y * H);
    float acc = 0.f;
    #pragma unroll
    for (int u = 0; u < 3; u++) {
        int yy = y + u - 1;
        if (yy < 0 || yy >= H) continue;
        #pragma unroll
        for (int v = 0; v < 3; v++) {
            int xx = x + v - 1;
            if (xx < 0 || xx >= H) continue;
            acc += sp[yy * H + xx] * wt[(u * 3 + v) * 128 + c];
        }
    }
    dst[r] = acc * scale[c];
}

__global__ void dw3x3_all_kernel(const float* __restrict__ sub, const float* __restrict__ wavw,
        const float* __restrict__ wavs, float* __restrict__ tt)
{
    int t = blockIdx.x * blockDim.x + threadIdx.x;
    if (t < 3211264)      dw3_body<28>(t,           sub,           wavw,        wavs,       tt);
    else if (t < 4014080) dw3_body<14>(t - 3211264, sub + 3211264, wavw + 1152, wavs + 128, tt + 3211264);
    else if (t < 4214784) dw3_body<7> (t - 4014080, sub + 4014080, wavw + 2304, wavs + 256, tt + 4014080);
    else if (t < 4280320) dw3_body<4> (t - 4214784, sub + 4214784, wavw + 3456, wavs + 384, tt + 4214784);
    else if (t < 4296704) dw3_body<2> (t - 4280320, sub + 4280320, wavw + 4608, wavs + 512, tt + 4280320);
}

// ---------------- Haar IDWT (+ll add, crop) — levels 4..1
__global__ void idwt_kernel(const float* __restrict__ tl, const float* __restrict__ nxt,
        float* __restrict__ outp, int h2, int w2, int ho, int wo)
{
    int t = blockIdx.x * blockDim.x + threadIdx.x;
    int total = Bc * 32 * ho * wo;
    if (t >= total) return;
    int x = t % wo; int r = t / wo;
    int y = r % ho; r /= ho;
    int c = r & 31; int b = r >> 5;
    int y2 = y >> 1, x2 = x >> 1;
    size_t pl = (size_t)h2 * w2;
    size_t base = (size_t)(b * 128 + c * 4) * pl + y2 * w2 + x2;
    float ll = tl[base];
    if (nxt) ll += nxt[(size_t)(b * 32 + c) * pl + y2 * w2 + x2];
    float lh = tl[base + pl], hl = tl[base + 2 * pl], hh = tl[base + 3 * pl];
    float v;
    if ((y & 1) == 0) v = ((x & 1) == 0) ? (ll - lh - hl + hh) : (ll - lh + hl - hh);
    else              v = ((x & 1) == 0) ? (ll + lh - hl - hh) : (ll + lh + hl + hh);
    outp[t] = v * 0.5f;
}

// ---------------- fused idwt level-0 + base depthwise conv -> bf16 NHWC
__global__ void idwt_dwbase_kernel(const float* __restrict__ tl, const float* __restrict__ nxt,
        const float* __restrict__ src, const float* __restrict__ wt,
        const float* __restrict__ scale, const float* __restrict__ bias,
        bf16* __restrict__ dst_nhwc)
{
    int t = blockIdx.x * blockDim.x + threadIdx.x;
    if (t >= Bc * 32 * Nc) return;
    int x = t % Wcc; int r = t / Wcc;
    int y = r % Hc; r /= Hc;
    int c = r & 31; int b = r >> 5;
    int y2 = y >> 1, x2 = x >> 1;
    const size_t pl = 784;
    size_t base = (size_t)(b * 128 + c * 4) * pl + y2 * 28 + x2;
    float ll = tl[base] + nxt[(size_t)(b * 32 + c) * pl + y2 * 28 + x2];
    float lh = tl[base + pl], hl = tl[base + 2 * pl], hh = tl[base + 3 * pl];
    float v;
    if ((y & 1) == 0) v = ((x & 1) == 0) ? (ll - lh - hl + hh) : (ll - lh + hl - hh);
    else              v = ((x & 1) == 0) ? (ll + lh - hl - hh) : (ll + lh + hl + hh);
    float recon = v * 0.5f;
    const float* sp = src + (t - x - y * Wcc);
    float acc = 0.f;
    #pragma unroll
    for (int u = 0; u < 3; u++) {
        int yy = y + u - 1;
        if (yy < 0 || yy >= Hc) continue;
        #pragma unroll
        for (int vv2 = 0; vv2 < 3; vv2++) {
            int xx = x + vv2 - 1;
            if (xx < 0 || xx >= Wcc) continue;
            acc += sp[yy * Wcc + xx] * wt[(u * 3 + vv2) * 32 + c];
        }
    }
    acc = (acc + bias[c]) * scale[c] + recon;
    dst_nhwc[(((size_t)b * Hc + y) * Wcc + x) * 32 + c] = __float2bfloat16(acc);
}

// ---------------- merged weight prep
__global__ void wprep_kernel(const float* __restrict__ qw, const float* __restrict__ kv1w,
        const float* __restrict__ kv2w, const float* __restrict__ pw,
        const float* __restrict__ f1w, const float* __restrict__ f2w,
        const float* __restrict__ cpw, bf16* __restrict__ qwt, bf16* __restrict__ kv1wt,
        bf16* __restrict__ kv2wt, bf16* __restrict__ pwt, bf16* __restrict__ w1t,
        bf16* __restrict__ w2t, bf16* __restrict__ cpwt)
{
    int t = blockIdx.x * blockDim.x + threadIdx.x;
    if (t < 9216) {
        int n = t % 96, k = t / 96;
        qwt[n * 96 + k] = __float2bfloat16(qw[t]);
    } else if (t < 18432) {
        int u = t - 9216; int n = u % 96, k = u / 96;
        kv1wt[n * 96 + k] = __float2bfloat16(kv1w[u]);
    } else if (t < 27648) {
        int u = t - 18432; int n = u % 96, k = u / 96;
        kv2wt[n * 96 + k] = __float2bfloat16(kv2w[u]);
    } else if (t < 44032) {
        int u = t - 27648; int n = u % 128, k = u / 128;
        pwt[n * 128 + k] = __float2bfloat16(pw[u]);
    } else if (t < 109568) {
        int u = t - 44032; int n = u % 512, k = u / 512;
        w1t[(size_t)n * 128 + k] = __float2bfloat16(f1w[u]);
    } else if (t < 175104) {
        int u = t - 109568; int n = u % 128, k = u / 128;
        w2t[(size_t)n * 512 + k] = __float2bfloat16(f2w[u]);
    } else if (t < 184320) {
        int u = t - 175104; int co = u / 288, k = u % 288;
        cpwt[u] = __float2bfloat16(cpw[k * 32 + co]);
    }
}

// ---------------- cp2d implicit-GEMM MFMA + FUSED cn (LN over 32 ch + gelu)
__global__ __launch_bounds__(256) void cp2d_cn_kernel(const bf16* __restrict__ src,
        const bf16* __restrict__ wtc, const float* __restrict__ bias,
        const float* __restrict__ cnw, const float* __restrict__ cnb,
        bf16* __restrict__ attn_cat)
{
    __shared__ unsigned short in_s[10 * 400];
    __shared__ unsigned short w_s[32 * 296];
    int tid = threadIdx.x;
    int b = blockIdx.y;
    int ty = blockIdx.x / 7, tx = blockIdx.x % 7;
    for (int idx = tid; idx < 1152; idx += 256) {
        int co = idx / 36, j8 = (idx % 36) * 8;
        *(int4*)&w_s[co * 296 + j8] = *(const int4*)(wtc + co * 288 + j8);
    }
    {
        int idx = tid;
        if (idx < 200) {
            int cell = idx >> 1, half = idx & 1;
            int dy = cell / 10, dx = cell % 10;
            int gy = ty * 8 - 1 + dy, gx = tx * 8 - 1 + dx;
            int4 v0 = make_int4(0, 0, 0, 0), v1 = v0;
            if (gy >= 0 && gy < 56 && gx >= 0 && gx < 56) {
                const int4* gp = (const int4*)(src + ((((size_t)b * 56 + gy) * 56 + gx) * 32 + half * 16));
                v0 = gp[0]; v1 = gp[1];
            }
            *(int4*)&in_s[dy * 400 + dx * 40 + half * 16] = v0;
            *(int4*)&in_s[dy * 400 + dx * 40 + half * 16 + 8] = v1;
        }
    }
    __syncthreads();
    int wave = tid >> 6, lane = tid & 63;
    int ml = lane & 15, qd = lane >> 4;
    int m = wave * 16 + ml;
    int ly = m >> 3, lx = m & 7;
    f32x4 acc0 = {0.f, 0.f, 0.f, 0.f}, acc1 = {0.f, 0.f, 0.f, 0.f};
    #pragma unroll
    for (int u = 0; u < 3; u++)
    #pragma unroll
    for (int v = 0; v < 3; v++) {
        bf16x8 af = *(const bf16x8*)&in_s[(ly + u) * 400 + (lx + v) * 40 + qd * 8];
        int k = (u * 3 + v) * 32 + qd * 8;
        bf16x8 b0 = *(const bf16x8*)&w_s[ml * 296 + k];
        bf16x8 b1 = *(const bf16x8*)&w_s[(16 + ml) * 296 + k];
        acc0 = __builtin_amdgcn_mfma_f32_16x16x32_bf16(af, b0, acc0, 0, 0, 0);
        acc1 = __builtin_amdgcn_mfma_f32_16x16x32_bf16(af, b1, acc1, 0, 0, 0);
    }
    float bia0 = bias[ml], bia1 = bias[16 + ml];
    float g0 = cnw[ml], g1 = cnw[16 + ml];
    float be0 = cnb[ml], be1 = cnb[16 + ml];
    #pragma unroll
    for (int r = 0; r < 4; r++) {
        float c0 = acc0[r] + bia0;
        float c1 = acc1[r] + bia1;
        float s = c0 + c1, q = c0 * c0 + c1 * c1;
        #pragma unroll
        for (int o = 8; o; o >>= 1) { s += __shfl_xor(s, o); q += __shfl_xor(q, o); }
        float mean = s * (1.f / 32.f);
        float inv = rsqrtf(q * (1.f / 32.f) - mean * mean + EPSc);
        int mr = wave * 16 + qd * 4 + r;
        int ry = ty * 8 + (mr >> 3), rx = tx * 8 + (mr & 7);
        bf16* op = attn_cat + ((size_t)b * Nc + ry * 56 + rx) * 128 + 96;
        op[ml]      = __float2bfloat16(gelu_f((c0 - mean) * inv * g0 + be0));
        op[16 + ml] = __float2bfloat16(gelu_f((c1 - mean) * inv * g1 + be1));
    }
}

// ---------------- merged sr: both depthwise reductions in one launch
template<int KS, int LD>
__device__ __forceinline__ void sr_body(int t, const float* __restrict__ xa,
        const float* __restrict__ wt, const float* __restrict__ bias,
        float* __restrict__ outp)
{
    int c = t % Cac; int r = t / Cac;
    int j = r % LD; r /= LD;
    int i = r % LD; int b = r / LD;
    float acc = bias[c];
    for (int u = 0; u < KS; u++)
        for (int v = 0; v < KS; v++)
            acc += xa[(size_t)(b * Nc + (i * KS + u) * Wcc + (j * KS + v)) * Cac + c]
                 * wt[(u * KS + v) * Cac + c];
    outp[t] = acc;
}

__global__ void sr_all_kernel(const float* __restrict__ xa,
        const float* __restrict__ sr1w, const float* __restrict__ sr1b, float* __restrict__ x1p,
        const float* __restrict__ sr2w, const float* __restrict__ sr2b, float* __restrict__ x2p)
{
    int t = blockIdx.x * blockDim.x + threadIdx.x;
    if (t < 150528) sr_body<8, 7>(t, xa, sr1w, sr1b, x1p);
    else {
        int u = t - 150528;
        if (u < 602112) sr_body<4, 14>(u, xa, sr2w, sr2b, x2p);
    }
}

// ---------------- merged LN over 96 + gelu -> bf16 (both branches, one launch)
__global__ __launch_bounds__(256) void ln96_all_kernel(
        const float* __restrict__ s1, const float* __restrict__ g1,
        const float* __restrict__ b1, bf16* __restrict__ d1,
        const float* __restrict__ s2, const float* __restrict__ g2,
        const float* __restrict__ b2, bf16* __restrict__ d2)
{
    int wv = threadIdx.x >> 6, lane = threadIdx.x & 63;
    int row = blockIdx.x * 4 + wv;
    const float* sp; const float* g; const float* be; bf16* dst; int r;
    if (row < 1568)      { sp = s1; g = g1; be = b1; dst = d1; r = row; }
    else if (row < 7840) { sp = s2; g = g2; be = b2; dst = d2; r = row - 1568; }
    else return;
    sp += (size_t)r * 96;
    float x0 = sp[lane];
    float x1 = (lane < 32) ? sp[64 + lane] : 0.f;
    float s = x0 + x1, q = x0 * x0 + x1 * x1;
    for (int o = 32; o; o >>= 1) { s += __shfl_xor(s, o); q += __shfl_xor(q, o); }
    float mean = s * (1.f / 96.f);
    float inv = rsqrtf(q * (1.f / 96.f) - mean * mean + EPSc);
    dst[(size_t)r * 96 + lane] =
        __float2bfloat16(gelu_f((x0 - mean) * inv * g[lane] + be[lane]));
    if (lane < 32)
        dst[(size_t)r * 96 + 64 + lane] =
            __float2bfloat16(gelu_f((x1 - mean) * inv * g[64 + lane] + be[64 + lane]));
}

// ---------------- MFMA GEMM (MR=1, templated K-depth BK). OMODE: 0 = fp32
// row-major, 1 = bf16 row-major, 2 = fp32 head-major Q layout (B,8,N,12)
template<int NF, int BK, bool GELU, bool RES, int OMODE>
__global__ __launch_bounds__(256) void gemm_kernel(const bf16* __restrict__ A,
        const bf16* __restrict__ Wt, const float* __restrict__ bias,
        const float* __restrict__ res, void* __restrict__ outp,
        int M, int K, int Nt)
{
    constexpr int TN = 16 * NF;
    __shared__ unsigned short As[64][BK + 8];
    __shared__ unsigned short Bs[TN][BK + 8];
    int tid = threadIdx.x;
    int wave = tid >> 6, lane = tid & 63;
    int m0 = blockIdx.y * 64, n0 = blockIdx.x * TN;
    f32x4 acc[NF];
    #pragma unroll
    for (int f = 0; f < NF; f++) acc[f] = (f32x4){0.f, 0.f, 0.f, 0.f};

    int ar = tid >> 2, ac = (tid & 3) << 3;
    int ml = wave * 16 + (lane & 15);
    int qd = lane >> 4;

    for (int k0 = 0; k0 < K; k0 += BK) {
        #pragma unroll
        for (int i = 0; i < BK / 32; i++) {
            int cc = ac + i * 32;
            int4 av = make_int4(0, 0, 0, 0);
            if (m0 + ar < M) av = *(const int4*)(A + (size_t)(m0 + ar) * K + k0 + cc);
            *(int4*)&As[ar][cc] = av;
        }
        for (int idx = tid; idx < TN * (BK / 8); idx += 256) {
            int br = idx / (BK / 8), bc = (idx % (BK / 8)) * 8;
            *(int4*)&Bs[br][bc] = *(const int4*)(Wt + (size_t)(n0 + br) * K + k0 + bc);
        }
        __syncthreads();
        #pragma unroll
        for (int kk = 0; kk < BK / 32; kk++) {
            bf16x8 af = *(const bf16x8*)&As[ml][kk * 32 + qd * 8];
            #pragma unroll
            for (int f = 0; f < NF; f++) {
                bf16x8 bfv = *(const bf16x8*)&Bs[f * 16 + (lane & 15)][kk * 32 + qd * 8];
                acc[f] = __builtin_amdgcn_mfma_f32_16x16x32_bf16(af, bfv, acc[f], 0, 0, 0);
            }
        }
        __syncthreads();
    }
    #pragma unroll
    for (int f = 0; f < NF; f++) {
        int n = n0 + f * 16 + (lane & 15);
        #pragma unroll
        for (int r = 0; r < 4; r++) {
            int m = m0 + wave * 16 + qd * 4 + r;
            if (m >= M) continue;
            float v = acc[f][r];
            if (bias) v += bias[n];
            if (GELU) v = gelu_f(v);
            if (RES)  v += res[(size_t)m * Nt + n];
            if (OMODE == 1)
                ((bf16*)outp)[(size_t)m * Nt + n] = __float2bfloat16(v);
            else if (OMODE == 2) {
                int b = m / Nc, nn = m - b * Nc;
                int h = n / 12, d = n - h * 12;
                ((float*)outp)[(((size_t)(b * 8 + h)) * Nc + nn) * 12 + d] = v;
            } else
                ((float*)outp)[(size_t)m * Nt + n] = v;
        }
    }
}

// ---------------- proj GEMM (K=128, TN=128 full rows) + bias + residual + FUSED LN2.
// Writes XRES fp32 (fc2 residual) and XNb bf16 (fc1 input); ln2 kernel eliminated.
__global__ __launch_bounds__(256) void proj_ln_kernel(const bf16* __restrict__ A,
        const bf16* __restrict__ Wt, const float* __restrict__ bias,
        const float* __restrict__ res, const float* __restrict__ g,
        const float* __restrict__ be, float* __restrict__ xres, bf16* __restrict__ xnb)
{
    __shared__ unsigned short As[64][72];
    __shared__ unsigned short Bs[128][72];
    int tid = threadIdx.x;
    int wave = tid >> 6, lane = tid & 63;
    int m0 = blockIdx.x * 64;
    f32x4 acc[8];
    #pragma unroll
    for (int f = 0; f < 8; f++) acc[f] = (f32x4){0.f, 0.f, 0.f, 0.f};

    int ar = tid >> 2, ac = (tid & 3) << 3;
    int ml = lane & 15, qd = lane >> 4;
    int mlw = wave * 16 + ml;

    for (int k0 = 0; k0 < 128; k0 += 64) {
        #pragma unroll
        for (int i = 0; i < 2; i++) {
            int cc = ac + i * 32;
            *(int4*)&As[ar][cc] = *(const int4*)(A + (size_t)(m0 + ar) * 128 + k0 + cc);
        }
        for (int idx = tid; idx < 1024; idx += 256) {
            int br = idx >> 3, bc = (idx & 7) * 8;
            *(int4*)&Bs[br][bc] = *(const int4*)(Wt + (size_t)br * 128 + k0 + bc);
        }
        __syncthreads();
        #pragma unroll
        for (int kk = 0; kk < 2; kk++) {
            bf16x8 af = *(const bf16x8*)&As[mlw][kk * 32 + qd * 8];
            #pragma unroll
            for (int f = 0; f < 8; f++) {
                bf16x8 bfv = *(const bf16x8*)&Bs[f * 16 + ml][kk * 32 + qd * 8];
                acc[f] = __builtin_amdgcn_mfma_f32_16x16x32_bf16(af, bfv, acc[f], 0, 0, 0);
            }
        }
        __syncthreads();
    }
    float bia[8], gg[8], bb[8];
    #pragma unroll
    for (int f = 0; f < 8; f++) {
        int n = f * 16 + ml;
        bia[f] = bias[n]; gg[f] = g[n]; bb[f] = be[n];
    }
    #pragma unroll
    for (int r = 0; r < 4; r++) {
        int m = m0 + wave * 16 + qd * 4 + r;
        float vv[8];
        float s = 0.f, q = 0.f;
        #pragma unroll
        for (int f = 0; f < 8; f++) {
            int n = f * 16 + ml;
            float v = acc[f][r] + bia[f] + res[(size_t)m * 128 + n];
            vv[f] = v; s += v; q += v * v;
        }
        #pragma unroll
        for (int o = 8; o; o >>= 1) { s += __shfl_xor(s, o); q += __shfl_xor(q, o); }
        float mean = s * (1.f / 128.f);
        float inv = rsqrtf(q * (1.f / 128.f) - mean * mean + EPSc);
        #pragma unroll
        for (int f = 0; f < 8; f++) {
            int n = f * 16 + ml;
            xres[(size_t)m * 128 + n] = vv[f];
            xnb[(size_t)m * 128 + n] =
                __float2bfloat16((vv[f] - mean) * inv * gg[f] + bb[f]);
        }
    }
}

// ---------------- attention body: round-1 proven shape + raw v_exp_f32 (125us):
// fp32 K/V in LDS, 1 query/thread, branchless single-pass softmax.
template<int L>
__device__ __forceinline__ void attn_body(const float* __restrict__ qh,
        const float* __restrict__ kv, int hl, int h, int b,
        float* kb, float* vb, bf16* __restrict__ attn_cat)
{
    for (int idx = threadIdx.x; idx < L * 3; idx += 256) {
        int l = idx / 3, f = idx % 3;
        const float4* kp = (const float4*)(kv + (size_t)(b * L + l) * 96 + hl * 12) + f;
        float4 kk = kp[0];
        float4 vv = kp[12];
        *(float4*)&kb[l * 12 + f * 4] = kk;
        *(float4*)&vb[l * 12 + f * 4] = vv;
    }
    int n = blockIdx.x * 256 + threadIdx.x;
    bool act = (n < Nc);
    int nn = act ? n : (Nc - 1);
    const float4* qp = (const float4*)(qh + (((size_t)(b * 8 + h)) * Nc + nn) * 12);
    float4 q0 = qp[0], q1 = qp[1], q2 = qp[2];
    const float PRE = SCALEc * 1.4426950408889634f;   /* scale * log2(e) */
    q0.x *= PRE; q0.y *= PRE; q0.z *= PRE; q0.w *= PRE;
    q1.x *= PRE; q1.y *= PRE; q1.z *= PRE; q1.w *= PRE;
    q2.x *= PRE; q2.y *= PRE; q2.z *= PRE; q2.w *= PRE;
    __syncthreads();

    float den = 0.f;
    float o[12];
    #pragma unroll
    for (int d = 0; d < 12; d++) o[d] = 0.f;

    #pragma unroll 4
    for (int l = 0; l < L; l++) {
        const float4 k0 = *(const float4*)&kb[l * 12];
        const float4 k1 = *(const float4*)&kb[l * 12 + 4];
        const float4 k2 = *(const float4*)&kb[l * 12 + 8];
        float s0 = q0.x * k0.x + q0.y * k0.y + q0.z * k0.z + q0.w * k0.w;
        float s1 = q1.x * k1.x + q1.y * k1.y + q1.z * k1.z + q1.w * k1.w;
        float s2 = q2.x * k2.x + q2.y * k2.y + q2.z * k2.z + q2.w * k2.w;
        float e = fast_exp2(s0 + s1 + s2);
        den += e;
        const float4 v0 = *(const float4*)&vb[l * 12];
        const float4 v1 = *(const float4*)&vb[l * 12 + 4];
        const float4 v2 = *(const float4*)&vb[l * 12 + 8];
        o[0] += e * v0.x; o[1]  += e * v0.y; o[2]  += e * v0.z; o[3]  += e * v0.w;
        o[4] += e * v1.x; o[5]  += e * v1.y; o[6]  += e * v1.z; o[7]  += e * v1.w;
        o[8] += e * v2.x; o[9]  += e * v2.y; o[10] += e * v2.z; o[11] += e * v2.w;
    }
    if (act) {
        float rden = 1.f / den;
        bf16* op = attn_cat + (size_t)(b * Nc + n) * 128 + h * 12;
        #pragma unroll
        for (int d = 0; d < 12; d++) op[d] = __float2bfloat16(o[d] * rden);
    }
}

__global__ __launch_bounds__(256) void attn_kernel(const float* __restrict__ qh,
        const float* __restrict__ kv1, const float* __restrict__ kv2,
        bf16* __restrict__ attn_cat)
{
    __shared__ float kb[196 * 12];
    __shared__ float vb[196 * 12];
    int h = blockIdx.y, b = blockIdx.z;
    if (h < 4) attn_body<49> (qh, kv1, h,     h, b, kb, vb, attn_cat);
    else       attn_body<196>(qh, kv2, h - 4, h, b, kb, vb, attn_cat);
}

extern "C" void kernel_launch(void* const* d_in, const int* in_sizes, int n_in,
                              void* d_out, int out_size, void* d_ws, size_t ws_size,
                              hipStream_t stream)
{
    const float* x    = (const float*)d_in[0];
    const float* ln1w = (const float*)d_in[3];
    const float* ln1b = (const float*)d_in[4];
    const float* ln2w = (const float*)d_in[5];
    const float* ln2b = (const float*)d_in[6];
    const float* qw   = (const float*)d_in[7];
    const float* kv1w = (const float*)d_in[8];
    const float* kv2w = (const float*)d_in[9];
    const float* sr1w = (const float*)d_in[10];
    const float* sr1b = (const float*)d_in[11];
    const float* sr2w = (const float*)d_in[12];
    const float* sr2b = (const float*)d_in[13];
    const float* an1w = (const float*)d_in[14];
    const float* an1b = (const float*)d_in[15];
    const float* an2w = (const float*)d_in[16];
    const float* an2b = (const float*)d_in[17];
    const float* wbw  = (const float*)d_in[18];
    const float* wbb  = (const float*)d_in[19];
    const float* wbs  = (const float*)d_in[20];
    const float* wavw = (const float*)d_in[21];
    const float* wavs = (const float*)d_in[22];
    const float* cpw  = (const float*)d_in[23];
    const float* cpb  = (const float*)d_in[24];
    const float* cnw  = (const float*)d_in[25];
    const float* cnb  = (const float*)d_in[26];
    const float* pw   = (const float*)d_in[27];
    const float* pb   = (const float*)d_in[28];
    const float* f1w  = (const float*)d_in[29];
    const float* f1b  = (const float*)d_in[30];
    const float* f2w  = (const float*)d_in[31];
    const float* f2b  = (const float*)d_in[32];
    float* dout = (float*)d_out;
    float* ws = (float*)d_ws;

    float* XA    = ws;                      // 9,633,792
    float* QB    = ws + 9633792;            // head-major Q (B,8,N,12)
    float* XRES  = ws;                      // overlay
    bf16*  XNb   = (bf16*)(ws + 12845056);
    bf16*  XAb   = (bf16*)(ws + 19267584);
    bf16*  ACATb = (bf16*)(ws + 24084480);
    float* XCI   = ws + 30507008;
    float* SUB   = ws + 33718272;
    float* TT    = ws + 38014976;
    float* RA    = ws + 42311680;
    float* RB    = ws + 45522944;
    float* X1P   = ws + 48734208;
    float* X2P   = ws + 48884736;
    bf16*  X1Bb  = (bf16*)(ws + 49486848);
    bf16*  X2Bb  = (bf16*)(ws + 49562112);
    float* KV1   = ws + 49863168;
    float* KV2   = ws + 50013696;
    bf16*  WTB   = (bf16*)(ws + 50615808);
    bf16*  qwt   = WTB;
    bf16*  kv1wt = WTB + 9216;
    bf16*  kv2wt = WTB + 18432;
    bf16*  pwt   = WTB + 27648;
    bf16*  w1t   = WTB + 44032;
    bf16*  w2t   = WTB + 109568;
    bf16*  cpwt  = WTB + 175104;
    bf16*  Hb    = (bf16*)(ws + 24084480);
    bf16*  CIMGb = (bf16*)SUB;
    float* S0 = SUB;            float* T0 = TT;
    float* S1 = SUB + 3211264;  float* T1 = TT + 3211264;
    float* S2 = SUB + 4014080;  float* T2 = TT + 4014080;
    float* S3 = SUB + 4214784;  float* T3 = TT + 4214784;
    float* S4 = SUB + 4280320;  float* T4 = TT + 4280320;

    // 0. weight preps (single merged launch)
    wprep_kernel<<<720, 256, 0, stream>>>(qw, kv1w, kv2w, pw, f1w, f2w, cpw,
                                          qwt, kv1wt, kv2wt, pwt, w1t, w2t, cpwt);

    // 1. LN1
    ln1_kernel<<<25088, 256, 0, stream>>>(x, ln1w, ln1b, XA, XAb, XCI);

    // 2. DWT cascade (sequential on LL)
    dwt_kernel<<<3136, 256, 0, stream>>>(XCI, 1, 56, 56, 28, 28, S0);
    dwt_kernel<<<784,  256, 0, stream>>>(S0, 4, 28, 28, 14, 14, S1);
    dwt_kernel<<<196,  256, 0, stream>>>(S1, 4, 14, 14, 7, 7,   S2);
    dwt_kernel<<<64,   256, 0, stream>>>(S2, 4, 7, 7,   4, 4,   S3);
    dwt_kernel<<<16,   256, 0, stream>>>(S3, 4, 4, 4,   2, 2,   S4);

    // 3. ALL wavelet depthwise convs in one launch
    dw3x3_all_kernel<<<16784, 256, 0, stream>>>(SUB, wavw, wavs, TT);

    // 4. IDWT cascade levels 4..1
    idwt_kernel<<<64,   256, 0, stream>>>(T4, nullptr, RA, 2, 2, 4, 4);
    idwt_kernel<<<196,  256, 0, stream>>>(T3, RA, RB, 4, 4, 7, 7);
    idwt_kernel<<<784,  256, 0, stream>>>(T2, RB, RA, 7, 7, 14, 14);
    idwt_kernel<<<3136, 256, 0, stream>>>(T1, RA, RB, 14, 14, 28, 28);

    // 5. fused idwt level-0 + base depthwise conv -> bf16 NHWC
    idwt_dwbase_kernel<<<12544, 256, 0, stream>>>(T0, RB, XCI, wbw, wbs, wbb, CIMGb);

    // 6. cp2d implicit-GEMM MFMA + fused cn -> ACATb[96:128]
    cp2d_cn_kernel<<<dim3(49, 32), 256, 0, stream>>>(CIMGb, cpwt, cpb, cnw, cnb, ACATb);

    // 7. merged spatial reductions
    sr_all_kernel<<<2940, 256, 0, stream>>>(XA, sr1w, sr1b, X1P, sr2w, sr2b, X2P);

    // 8. merged LN96 + gelu -> bf16
    ln96_all_kernel<<<1960, 256, 0, stream>>>(X1P, an1w, an1b, X1Bb,
                                              X2P, an2w, an2b, X2Bb);

    // 9. q / kv GEMMs (q -> head-major)
    gemm_kernel<6,32,false,false,2><<<dim3(1, 1568), 256, 0, stream>>>(XAb,  qwt,   nullptr, nullptr, QB,  100352, 96, 96);
    gemm_kernel<6,32,false,false,0><<<dim3(1, 25),   256, 0, stream>>>(X1Bb, kv1wt, nullptr, nullptr, KV1, 1568,   96, 96);
    gemm_kernel<6,32,false,false,0><<<dim3(1, 98),   256, 0, stream>>>(X2Bb, kv2wt, nullptr, nullptr, KV2, 6272,   96, 96);

    // 10. merged attention -> ACATb[0:96]
    attn_kernel<<<dim3(13, 8, 32), 256, 0, stream>>>(QB, KV1, KV2, ACATb);

    // 11. proj + bias + residual(x) + FUSED LN2 -> XRES fp32 + XNb bf16
    proj_ln_kernel<<<1568, 256, 0, stream>>>(ACATb, pwt, pb, x, ln2w, ln2b, XRES, XNb);

    // 12. fc1 + bias + gelu -> Hb bf16  (BK=64)
    gemm_kernel<4,64,true,false,1><<<dim3(8, 1568), 256, 0, stream>>>(XNb, w1t, f1b, nullptr, Hb, 100352, 128, 512);

    // 13. fc2 + bias + residual(XRES) -> d_out fp32  (BK=64)
    gemm_kernel<4,64,false,true,0><<<dim3(2, 1568), 256, 0, stream>>>(Hb, w2t, f2b, XRES, dout, 100352, 512, 128);
}